// Round 10
// baseline (260.793 us; speedup 1.0000x reference)
//
#include <hip/hip_runtime.h>
#include <hip/hip_bf16.h>
#include <hip/hip_cooperative_groups.h>
#include <stdint.h>

namespace cg = cooperative_groups;

#define H_DIM 1024
#define QMAX 127.0f
#define CLIP 2.5f

typedef __attribute__((ext_vector_type(4))) float f32x4;
typedef __attribute__((ext_vector_type(4))) int i32x4;
typedef __attribute__((ext_vector_type(8))) short bf16x8;
typedef __attribute__((ext_vector_type(8))) unsigned short u16x8;
typedef __attribute__((address_space(3))) void lds_void;
typedef const __attribute__((address_space(1))) void gmem_void;

__device__ __forceinline__ unsigned short quant_bf16(float x, float s) {
  const float q = rintf(fminf(fmaxf(x, -CLIP), CLIP) * s);
  return (unsigned short)(__float_as_uint(q) >> 16);
}

__device__ __forceinline__ int quant_i8(float x, float s) {
  return (int)rintf(fminf(fmaxf(x, -CLIP), CLIP) * s);  // in [-127,127]
}

__device__ __forceinline__ unsigned short f2bf_rne(float f) {
  const unsigned u = __float_as_uint(f);
  return (unsigned short)((u + 0x7FFFu + ((u >> 16) & 1u)) >> 16);
}

__device__ __forceinline__ float bf2f(unsigned short u) {
  return __uint_as_float((unsigned)u << 16);
}

__device__ __forceinline__ unsigned pack4_i8(float4 v, float s) {
  return ((unsigned)(unsigned char)(signed char)quant_i8(v.x, s)) |
         ((unsigned)(unsigned char)(signed char)quant_i8(v.y, s) << 8) |
         ((unsigned)(unsigned char)(signed char)quant_i8(v.z, s) << 16) |
         ((unsigned)(unsigned char)(signed char)quant_i8(v.w, s) << 24);
}

// ===========================================================================
// coop_quant: fused absmax(hidden,weight) + grid.sync + quantize both to i8.
// 1024 blocks x 256 thr (4 blocks/CU, co-resident).  scales pre-zeroed.
// Phase 2 re-reads are L3-hot (134 MB << 256 MB Infinity Cache).
// ===========================================================================
__global__ __launch_bounds__(256) void coop_quant_kernel(
    const float* __restrict__ hidden, const float* __restrict__ weight,
    float* __restrict__ scales, signed char* __restrict__ Aq8,
    signed char* __restrict__ Wq8, long nh, long nw) {
  const long tid = (long)blockIdx.x * blockDim.x + threadIdx.x;
  const long nthr = (long)gridDim.x * blockDim.x;

  // ---- phase 1: absmax of clip(x) for both tensors ----
  float mh = 0.f, mw = 0.f;
  for (long i = tid * 4; i < nh; i += nthr * 4) {
    const float4 v = *reinterpret_cast<const float4*>(hidden + i);
    mh = fmaxf(mh, fmaxf(fmaxf(fabsf(v.x), fabsf(v.y)), fmaxf(fabsf(v.z), fabsf(v.w))));
  }
  for (long i = tid * 4; i < nw; i += nthr * 4) {
    const float4 v = *reinterpret_cast<const float4*>(weight + i);
    mw = fmaxf(mw, fmaxf(fmaxf(fabsf(v.x), fabsf(v.y)), fmaxf(fabsf(v.z), fabsf(v.w))));
  }
  mh = fminf(mh, CLIP);
  mw = fminf(mw, CLIP);
#pragma unroll
  for (int off = 32; off > 0; off >>= 1) {
    mh = fmaxf(mh, __shfl_down(mh, off));
    mw = fmaxf(mw, __shfl_down(mw, off));
  }
  __shared__ float red[8];
  const int lane = threadIdx.x & 63, w = threadIdx.x >> 6;
  if (lane == 0) { red[w] = mh; red[4 + w] = mw; }
  __syncthreads();
  if (threadIdx.x == 0) {
    atomicMax(reinterpret_cast<unsigned int*>(&scales[0]),
              __float_as_uint(fmaxf(fmaxf(red[0], red[1]), fmaxf(red[2], red[3]))));
    atomicMax(reinterpret_cast<unsigned int*>(&scales[1]),
              __float_as_uint(fmaxf(fmaxf(red[4], red[5]), fmaxf(red[6], red[7]))));
  }

  cg::this_grid().sync();

  // ---- phase 2: quantize (agent-scope loads: cross-XCD safe) ----
  const float amax_h = fmaxf(
      __hip_atomic_load(&scales[0], __ATOMIC_RELAXED, __HIP_MEMORY_SCOPE_AGENT), 1e-8f);
  const float amax_w = fmaxf(
      __hip_atomic_load(&scales[1], __ATOMIC_RELAXED, __HIP_MEMORY_SCOPE_AGENT), 1e-8f);
  const float sh = QMAX / amax_h, sw = QMAX / amax_w;

  for (long i = tid * 8; i < nh; i += nthr * 8) {
    const float4 v0 = *reinterpret_cast<const float4*>(hidden + i);
    const float4 v1 = *reinterpret_cast<const float4*>(hidden + i + 4);
    uint2 o; o.x = pack4_i8(v0, sh); o.y = pack4_i8(v1, sh);
    *reinterpret_cast<uint2*>(Aq8 + i) = o;
  }
  for (long i = tid * 8; i < nw; i += nthr * 8) {
    const float4 v0 = *reinterpret_cast<const float4*>(weight + i);
    const float4 v1 = *reinterpret_cast<const float4*>(weight + i + 4);
    uint2 o; o.x = pack4_i8(v0, sw); o.y = pack4_i8(v1, sw);
    *reinterpret_cast<uint2*>(Wq8 + i) = o;
  }
}

// ---------------------------------------------------------------------------
// Legacy front-end (r9-validated fallback).
// ---------------------------------------------------------------------------
__global__ __launch_bounds__(256) void absmax_clip_kernel(
    const float* __restrict__ x, long n, float* __restrict__ out) {
  float m = 0.f;
  const long stride = (long)gridDim.x * blockDim.x * 4;
  for (long i = ((long)blockIdx.x * blockDim.x + threadIdx.x) * 4; i < n; i += stride) {
    const float4 v = *reinterpret_cast<const float4*>(x + i);
    m = fmaxf(m, fmaxf(fmaxf(fabsf(v.x), fabsf(v.y)), fmaxf(fabsf(v.z), fabsf(v.w))));
  }
  m = fminf(m, CLIP);
#pragma unroll
  for (int off = 32; off > 0; off >>= 1) m = fmaxf(m, __shfl_down(m, off));
  __shared__ float red[4];
  const int lane = threadIdx.x & 63, w = threadIdx.x >> 6;
  if (lane == 0) red[w] = m;
  __syncthreads();
  if (threadIdx.x == 0) {
    const float mm = fmaxf(fmaxf(red[0], red[1]), fmaxf(red[2], red[3]));
    atomicMax(reinterpret_cast<unsigned int*>(out), __float_as_uint(mm));
  }
}

__global__ __launch_bounds__(256) void quant_kernel(
    const float* __restrict__ x, unsigned short* __restrict__ q,
    const float* __restrict__ amax_p, long n) {
  const float s = QMAX / fmaxf(amax_p[0], 1e-8f);
  const long stride = (long)gridDim.x * blockDim.x * 4;
  for (long i = ((long)blockIdx.x * blockDim.x + threadIdx.x) * 4; i < n; i += stride) {
    const float4 v = *reinterpret_cast<const float4*>(x + i);
    ushort4 o;
    o.x = quant_bf16(v.x, s);
    o.y = quant_bf16(v.y, s);
    o.z = quant_bf16(v.z, s);
    o.w = quant_bf16(v.w, s);
    *reinterpret_cast<ushort4*>(q + i) = o;
  }
}

__global__ __launch_bounds__(256) void quant8_kernel(
    const float* __restrict__ x, signed char* __restrict__ q,
    const float* __restrict__ amax_p, long n) {
  const float s = QMAX / fmaxf(amax_p[0], 1e-8f);
  const long stride = (long)gridDim.x * blockDim.x * 8;
  for (long i = ((long)blockIdx.x * blockDim.x + threadIdx.x) * 8; i < n; i += stride) {
    const float4 v0 = *reinterpret_cast<const float4*>(x + i);
    const float4 v1 = *reinterpret_cast<const float4*>(x + i + 4);
    uint2 o; o.x = pack4_i8(v0, s); o.y = pack4_i8(v1, s);
    *reinterpret_cast<uint2*>(q + i) = o;
  }
}

// ===========================================================================
// gemm_s8 (r9-validated): int8 GEMM, NO residual.
// gbf[m][n] = bf16((i32 dot)*inv_s + b[n]).  128x128 tile, BK=64 (16 iters),
// mfma_i32_16x16x64_i8, triple-buffered counted-vmcnt 1-barrier loop,
// verified swizzle (0 conflicts), bf16 LDS-bounce coalesced epilogue.
// ===========================================================================
#define BMs 128
#define BNs 128
#define BKs8 64
#define NIT8 (H_DIM / BKs8) /* 16 */

__global__ __launch_bounds__(256) void gemm_s8_kernel(
    const signed char* __restrict__ Aq8, const signed char* __restrict__ Wq8,
    const float* __restrict__ bias, const float* __restrict__ scales,
    unsigned short* __restrict__ gbf, int M) {
  __shared__ __attribute__((aligned(16))) char SM8[49152];
  char* As = SM8;            // [3][128*64] i8
  char* Bs = SM8 + 24576;    // [3][128*64] i8

  const int nwg = (M / BMs) * 8;
  const int orig = blockIdx.x;
  const int cpx = nwg >> 3;
  const int wg = ((nwg & 7) == 0) ? ((orig & 7) * cpx + (orig >> 3)) : orig;
  const int bn = wg & 7, bm = wg >> 3;
  const int m0 = bm * BMs, n0 = bn * BNs;

  const int t = threadIdx.x;
  const int lane = t & 63, wid = t >> 6;
  const int wr = wid >> 1, wc = wid & 1;
  const int lrow = lane & 15, lgrp = lane >> 4;

  const float amax_h = fmaxf(scales[0], 1e-8f);
  const float amax_w = fmaxf(scales[1], 1e-8f);
  const float inv_s = (amax_h * amax_w) / (QMAX * QMAX);

  const int c0 = t, c1 = t + 256;
  const int r0 = c0 >> 2, r1 = c1 >> 2;
  const unsigned g0 = (unsigned)r0 * H_DIM + (unsigned)((((c0 & 3) ^ ((r0 >> 1) & 3))) * 16);
  const unsigned g1 = (unsigned)r1 * H_DIM + (unsigned)((((c1 & 3) ^ ((r1 >> 1) & 3))) * 16);
  const signed char* Ag = Aq8 + (size_t)m0 * H_DIM;
  const signed char* Bg = Wq8 + (size_t)n0 * H_DIM;

#define STAGE_T8(BUF, KQ)                                                      \
  { __builtin_amdgcn_global_load_lds((gmem_void*)(Ag + g0 + (KQ)),             \
        (lds_void*)(As + (BUF)*8192 + c0 * 16), 16, 0, 0);                     \
    __builtin_amdgcn_global_load_lds((gmem_void*)(Ag + g1 + (KQ)),             \
        (lds_void*)(As + (BUF)*8192 + c1 * 16), 16, 0, 0);                     \
    __builtin_amdgcn_global_load_lds((gmem_void*)(Bg + g0 + (KQ)),             \
        (lds_void*)(Bs + (BUF)*8192 + c0 * 16), 16, 0, 0);                     \
    __builtin_amdgcn_global_load_lds((gmem_void*)(Bg + g1 + (KQ)),             \
        (lds_void*)(Bs + (BUF)*8192 + c1 * 16), 16, 0, 0); }

  int offA[4], offB[4];
#pragma unroll
  for (int i = 0; i < 4; ++i) {
    const int r = wr * 64 + i * 16 + lrow;
    offA[i] = r * 64 + ((lgrp ^ ((r >> 1) & 3)) * 16);
  }
#pragma unroll
  for (int j = 0; j < 4; ++j) {
    const int r = wc * 64 + j * 16 + lrow;
    offB[j] = r * 64 + ((lgrp ^ ((r >> 1) & 3)) * 16);
  }

  i32x4 acc[4][4];
#pragma unroll
  for (int i = 0; i < 4; i++)
#pragma unroll
    for (int j = 0; j < 4; j++)
#pragma unroll
      for (int r = 0; r < 4; r++) acc[i][j][r] = 0;

  STAGE_T8(0, 0)
  STAGE_T8(1, BKs8)

  for (int it = 0; it < NIT8; ++it) {
    const int cb = it % 3;
    if (it + 1 < NIT8) {
      asm volatile("s_waitcnt vmcnt(4)" ::: "memory");
    } else {
      asm volatile("s_waitcnt vmcnt(0)" ::: "memory");
    }
    __builtin_amdgcn_s_barrier();

    i32x4 af[4], bfr[4];
#pragma unroll
    for (int i = 0; i < 4; ++i)
      af[i] = *reinterpret_cast<const i32x4*>(As + cb * 8192 + offA[i]);
#pragma unroll
    for (int j = 0; j < 4; ++j)
      bfr[j] = *reinterpret_cast<const i32x4*>(Bs + cb * 8192 + offB[j]);
    __builtin_amdgcn_s_setprio(1);
#pragma unroll
    for (int i = 0; i < 4; ++i)
#pragma unroll
      for (int j = 0; j < 4; ++j)
        acc[i][j] = __builtin_amdgcn_mfma_i32_16x16x64_i8(af[i], bfr[j], acc[i][j], 0, 0, 0);
    __builtin_amdgcn_s_setprio(0);

    if (it + 2 < NIT8) {
      STAGE_T8((it + 2) % 3, (unsigned)((it + 2) * BKs8))
    }
  }
#undef STAGE_T8
  __syncthreads();

  unsigned short* SMu = reinterpret_cast<unsigned short*>(SM8);
#pragma unroll
  for (int j = 0; j < 4; ++j) {
    const int cl = wc * 64 + j * 16 + lrow;
    const float bv = bias[n0 + cl];
#pragma unroll
    for (int i = 0; i < 4; ++i) {
      const int rl0 = wr * 64 + i * 16 + lgrp * 4;
#pragma unroll
      for (int r = 0; r < 4; ++r)
        SMu[(rl0 + r) * 136 + cl] = f2bf_rne((float)acc[i][j][r] * inv_s + bv);
    }
  }
  __syncthreads();
  {
    const int e_row = t >> 1, e_half = t & 1;
    unsigned short* dst = gbf + (size_t)(m0 + e_row) * H_DIM + n0 + e_half * 64;
    const unsigned short* src = SMu + e_row * 136 + e_half * 64;
#pragma unroll
    for (int c = 0; c < 8; ++c)
      *reinterpret_cast<u16x8*>(dst + c * 8) =
          *reinterpret_cast<const u16x8*>(src + c * 8);
  }
}

// ---------------------------------------------------------------------------
// ln_resid (r6-validated): y = bf16 g + fp32 resid; LayerNorm -> fp32 out.
// ---------------------------------------------------------------------------
__global__ __launch_bounds__(256) void ln_resid_kernel(
    const unsigned short* __restrict__ gbf, const float* __restrict__ resid,
    const float* __restrict__ gamma, const float* __restrict__ beta,
    float* __restrict__ out) {
  const int rl = threadIdx.x >> 7;
  const int c0 = (threadIdx.x & 127) * 8;
  const size_t base = ((size_t)blockIdx.x * 2 + rl) * H_DIM + c0;

  const u16x8 g = *reinterpret_cast<const u16x8*>(gbf + base);
  const float4 rA = *reinterpret_cast<const float4*>(resid + base);
  const float4 rB = *reinterpret_cast<const float4*>(resid + base + 4);
  float v[8];
  v[0] = bf2f(g[0]) + rA.x; v[1] = bf2f(g[1]) + rA.y;
  v[2] = bf2f(g[2]) + rA.z; v[3] = bf2f(g[3]) + rA.w;
  v[4] = bf2f(g[4]) + rB.x; v[5] = bf2f(g[5]) + rB.y;
  v[6] = bf2f(g[6]) + rB.z; v[7] = bf2f(g[7]) + rB.w;

  float s = 0.f, ss = 0.f;
#pragma unroll
  for (int k = 0; k < 8; ++k) { s += v[k]; ss += v[k] * v[k]; }
#pragma unroll
  for (int off = 32; off > 0; off >>= 1) {
    s += __shfl_down(s, off);
    ss += __shfl_down(ss, off);
  }
  __shared__ float red[4][2];
  const int lane = threadIdx.x & 63, w = threadIdx.x >> 6;
  if (lane == 0) { red[w][0] = s; red[w][1] = ss; }
  __syncthreads();
  const int wp = rl * 2;
  const float stot = red[wp][0] + red[wp + 1][0];
  const float sstot = red[wp][1] + red[wp + 1][1];
  const float mu = stot * (1.0f / H_DIM);
  const float var = fmaxf(sstot * (1.0f / H_DIM) - mu * mu, 0.f);
  const float rs = rsqrtf(var + 1e-12f);

  const float4 gA = *reinterpret_cast<const float4*>(gamma + c0);
  const float4 gB = *reinterpret_cast<const float4*>(gamma + c0 + 4);
  const float4 bA = *reinterpret_cast<const float4*>(beta + c0);
  const float4 bB = *reinterpret_cast<const float4*>(beta + c0 + 4);
  float4 oA, oB;
  oA.x = (v[0] - mu) * rs * gA.x + bA.x;
  oA.y = (v[1] - mu) * rs * gA.y + bA.y;
  oA.z = (v[2] - mu) * rs * gA.z + bA.z;
  oA.w = (v[3] - mu) * rs * gA.w + bA.w;
  oB.x = (v[4] - mu) * rs * gB.x + bB.x;
  oB.y = (v[5] - mu) * rs * gB.y + bB.y;
  oB.z = (v[6] - mu) * rs * gB.z + bB.z;
  oB.w = (v[7] - mu) * rs * gB.w + bB.w;
  *reinterpret_cast<float4*>(out + base) = oA;
  *reinterpret_cast<float4*>(out + base + 4) = oB;
}

// ===========================================================================
// Tier-3 fallback (round-1 validated): fused-quant bf16 GEMM + LN.
// ===========================================================================
#define BM 128
#define BN 128
#define BK 32

__global__ __launch_bounds__(256, 2) void gemm_fused_kernel(
    const float* __restrict__ A, const unsigned short* __restrict__ Wq,
    const float* __restrict__ bias, const float* __restrict__ resid,
    const float* __restrict__ scales, float* __restrict__ out, int M) {
  __shared__ unsigned short Asf[BM][40];
  __shared__ unsigned short Bsf[BN][40];
  const int nbm = M / BM;
  const int bm = blockIdx.x % nbm, bn = blockIdx.x / nbm;
  const int m0 = bm * BM, n0 = bn * BN;
  const int t = threadIdx.x;
  const int lane = t & 63, wid = t >> 6;
  const int wr = wid >> 1, wc = wid & 1;
  const int lrow = lane & 15, lgrp = lane >> 4;
  const float amax_h = fmaxf(scales[0], 1e-8f);
  const float amax_w = fmaxf(scales[1], 1e-8f);
  const float sh = QMAX / amax_h;
  const float inv_s = (amax_h * amax_w) / (QMAX * QMAX);
  f32x4 acc[4][4];
#pragma unroll
  for (int i = 0; i < 4; i++)
#pragma unroll
    for (int j = 0; j < 4; j++)
#pragma unroll
      for (int r = 0; r < 4; r++) acc[i][j][r] = 0.f;
  for (int k0 = 0; k0 < H_DIM; k0 += BK) {
#pragma unroll
    for (int j = 0; j < 4; ++j) {
      const int f = j * 256 + t;
      const int r = f >> 3, c4 = f & 7;
      const float4 v = *reinterpret_cast<const float4*>(A + (size_t)(m0 + r) * H_DIM + k0 + c4 * 4);
      ushort4 q;
      q.x = quant_bf16(v.x, sh); q.y = quant_bf16(v.y, sh);
      q.z = quant_bf16(v.z, sh); q.w = quant_bf16(v.w, sh);
      *reinterpret_cast<ushort4*>(&Asf[r][c4 * 4]) = q;
    }
#pragma unroll
    for (int j = 0; j < 2; ++j) {
      const int f = j * 256 + t;
      const int r = f >> 2, cb = f & 3;
      const uint4 v = *reinterpret_cast<const uint4*>(Wq + (size_t)(n0 + r) * H_DIM + k0 + cb * 8);
      *reinterpret_cast<uint4*>(&Bsf[r][cb * 8]) = v;
    }
    __syncthreads();
    bf16x8 af[4], bfr[4];
#pragma unroll
    for (int i = 0; i < 4; i++)
      af[i] = *reinterpret_cast<const bf16x8*>(&Asf[wr * 64 + i * 16 + lrow][lgrp * 8]);
#pragma unroll
    for (int j = 0; j < 4; j++)
      bfr[j] = *reinterpret_cast<const bf16x8*>(&Bsf[wc * 64 + j * 16 + lrow][lgrp * 8]);
#pragma unroll
    for (int i = 0; i < 4; i++)
#pragma unroll
      for (int j = 0; j < 4; j++)
        acc[i][j] = __builtin_amdgcn_mfma_f32_16x16x32_bf16(af[i], bfr[j], acc[i][j], 0, 0, 0);
    __syncthreads();
  }
#pragma unroll
  for (int j = 0; j < 4; j++) {
    const int col = n0 + wc * 64 + j * 16 + lrow;
    const float bv = bias[col];
#pragma unroll
    for (int i = 0; i < 4; i++) {
      const int row0 = m0 + wr * 64 + i * 16 + lgrp * 4;
#pragma unroll
      for (int r = 0; r < 4; r++) {
        const size_t off = (size_t)(row0 + r) * H_DIM + col;
        out[off] = acc[i][j][r] * inv_s + bv + resid[off];
      }
    }
  }
}

__global__ __launch_bounds__(256) void ln_kernel(
    float* __restrict__ y, const float* __restrict__ gamma,
    const float* __restrict__ beta) {
  const size_t base = (size_t)blockIdx.x * H_DIM + threadIdx.x * 4;
  const float4 v = *reinterpret_cast<const float4*>(y + base);
  float s = v.x + v.y + v.z + v.w;
  float ss = v.x * v.x + v.y * v.y + v.z * v.z + v.w * v.w;
#pragma unroll
  for (int off = 32; off > 0; off >>= 1) {
    s += __shfl_down(s, off);
    ss += __shfl_down(ss, off);
  }
  __shared__ float red[8];
  const int lane = threadIdx.x & 63, w = threadIdx.x >> 6;
  if (lane == 0) { red[w] = s; red[4 + w] = ss; }
  __syncthreads();
  const float stot = red[0] + red[1] + red[2] + red[3];
  const float sstot = red[4] + red[5] + red[6] + red[7];
  const float mu = stot * (1.0f / H_DIM);
  const float var = fmaxf(sstot * (1.0f / H_DIM) - mu * mu, 0.f);
  const float rs = rsqrtf(var + 1e-12f);
  const float4 g = *reinterpret_cast<const float4*>(gamma + threadIdx.x * 4);
  const float4 b = *reinterpret_cast<const float4*>(beta + threadIdx.x * 4);
  float4 o;
  o.x = (v.x - mu) * rs * g.x + b.x;
  o.y = (v.y - mu) * rs * g.y + b.y;
  o.z = (v.z - mu) * rs * g.z + b.z;
  o.w = (v.w - mu) * rs * g.w + b.w;
  *reinterpret_cast<float4*>(y + base) = o;
}

extern "C" void kernel_launch(void* const* d_in, const int* in_sizes, int n_in,
                              void* d_out, int out_size, void* d_ws, size_t ws_size,
                              hipStream_t stream) {
  const float* hidden = (const float*)d_in[0];
  const float* resid  = (const float*)d_in[1];
  const float* weight = (const float*)d_in[2];
  const float* bias   = (const float*)d_in[3];
  const float* gamma  = (const float*)d_in[4];
  const float* beta   = (const float*)d_in[5];
  float* out = (float*)d_out;

  const long nh = (long)in_sizes[0];   // B*S*H
  const int M = (int)(nh / H_DIM);     // 32768
  const long nw = (long)H_DIM * H_DIM;

  float* scales = (float*)d_ws;
  char* base = (char*)d_ws + 256;
  signed char* Wq8 = (signed char*)base;                    // 1 MB
  signed char* Aq8 = (signed char*)(base + nw);             // nh bytes
  unsigned short* gbf = (unsigned short*)(base + nw + nh);  // nh*2 bytes
  const size_t need1 = 256 + (size_t)nw + (size_t)nh * 3;
  const size_t need3 = 256 + (size_t)nw * 2;

  hipMemsetAsync(d_ws, 0, 8, stream);

  if (ws_size >= need1 && (M % BMs) == 0 && (M % 2) == 0 && (nh % 8) == 0) {
    // ---- main i8 path, cooperative fused front-end ----
    int dev = 0, coop_ok = 0;
    hipGetDevice(&dev);
    hipDeviceGetAttribute(&coop_ok, hipDeviceAttributeCooperativeLaunch, dev);
    bool used_coop = false;
    if (coop_ok) {
      long nh_a = nh, nw_a = nw;
      const float* h_a = hidden; const float* w_a = weight;
      float* s_a = scales; signed char* a_a = Aq8; signed char* q_a = Wq8;
      void* args[] = {(void*)&h_a, (void*)&w_a, (void*)&s_a,
                      (void*)&a_a, (void*)&q_a, (void*)&nh_a, (void*)&nw_a};
      hipError_t e = hipLaunchCooperativeKernel(
          (const void*)coop_quant_kernel, dim3(1024), dim3(256), args, 0, stream);
      used_coop = (e == hipSuccess);
    }
    if (!used_coop) {
      absmax_clip_kernel<<<2048, 256, 0, stream>>>(hidden, nh, scales + 0);
      absmax_clip_kernel<<<256, 256, 0, stream>>>(weight, nw, scales + 1);
      quant8_kernel<<<512, 256, 0, stream>>>(weight, Wq8, scales + 1, nw);
      quant8_kernel<<<2048, 256, 0, stream>>>(hidden, Aq8, scales + 0, nh);
    }
    gemm_s8_kernel<<<(M / BMs) * (H_DIM / BNs), 256, 0, stream>>>(
        Aq8, Wq8, bias, scales, gbf, M);
    ln_resid_kernel<<<M / 2, 256, 0, stream>>>(gbf, resid, gamma, beta, out);
  } else if (ws_size >= need3 && (M % BM) == 0) {
    // ---- tier-3 bf16 fallback ----
    unsigned short* Wqf = (unsigned short*)base;
    absmax_clip_kernel<<<2048, 256, 0, stream>>>(hidden, nh, scales + 0);
    absmax_clip_kernel<<<256, 256, 0, stream>>>(weight, nw, scales + 1);
    quant_kernel<<<1024, 256, 0, stream>>>(weight, Wqf, scales + 1, nw);
    gemm_fused_kernel<<<(M / BM) * (H_DIM / BN), 256, 0, stream>>>(
        hidden, Wqf, bias, resid, scales, out, M);
    ln_kernel<<<M, 256, 0, stream>>>(out, gamma, beta);
  }
}

// Round 11
// 202.638 us; speedup vs baseline: 1.2870x; 1.2870x over previous
//
#include <hip/hip_runtime.h>
#include <hip/hip_bf16.h>
#include <stdint.h>

#define H_DIM 1024
#define QMAX 127.0f
#define CLIP 2.5f

typedef __attribute__((ext_vector_type(4))) float f32x4;
typedef __attribute__((ext_vector_type(4))) int i32x4;
typedef __attribute__((ext_vector_type(8))) short bf16x8;
typedef __attribute__((ext_vector_type(8))) unsigned short u16x8;
typedef __attribute__((address_space(3))) void lds_void;
typedef const __attribute__((address_space(1))) void gmem_void;

__device__ __forceinline__ unsigned short quant_bf16(float x, float s) {
  const float q = rintf(fminf(fmaxf(x, -CLIP), CLIP) * s);
  return (unsigned short)(__float_as_uint(q) >> 16);
}

__device__ __forceinline__ int quant_i8(float x, float s) {
  return (int)rintf(fminf(fmaxf(x, -CLIP), CLIP) * s);  // in [-127,127]
}

__device__ __forceinline__ unsigned short f2bf_rne(float f) {
  const unsigned u = __float_as_uint(f);
  return (unsigned short)((u + 0x7FFFu + ((u >> 16) & 1u)) >> 16);
}

__device__ __forceinline__ float bf2f(unsigned short u) {
  return __uint_as_float((unsigned)u << 16);
}

__device__ __forceinline__ unsigned pack4_i8(float4 v, float s) {
  return ((unsigned)(unsigned char)(signed char)quant_i8(v.x, s)) |
         ((unsigned)(unsigned char)(signed char)quant_i8(v.y, s) << 8) |
         ((unsigned)(unsigned char)(signed char)quant_i8(v.z, s) << 16) |
         ((unsigned)(unsigned char)(signed char)quant_i8(v.w, s) << 24);
}

// ---------------------------------------------------------------------------
// absmax of clip(x,-CLIP,CLIP) (n%4==0), atomicMax into *out (pre-zeroed).
// ---------------------------------------------------------------------------
__global__ __launch_bounds__(256) void absmax_clip_kernel(
    const float* __restrict__ x, long n, float* __restrict__ out) {
  float m = 0.f;
  const long stride = (long)gridDim.x * blockDim.x * 4;
  for (long i = ((long)blockIdx.x * blockDim.x + threadIdx.x) * 4; i < n; i += stride) {
    const float4 v = *reinterpret_cast<const float4*>(x + i);
    m = fmaxf(m, fmaxf(fmaxf(fabsf(v.x), fabsf(v.y)), fmaxf(fabsf(v.z), fabsf(v.w))));
  }
  m = fminf(m, CLIP);
#pragma unroll
  for (int off = 32; off > 0; off >>= 1) m = fmaxf(m, __shfl_down(m, off));
  __shared__ float red[4];
  const int lane = threadIdx.x & 63, w = threadIdx.x >> 6;
  if (lane == 0) red[w] = m;
  __syncthreads();
  if (threadIdx.x == 0) {
    const float mm = fmaxf(fmaxf(red[0], red[1]), fmaxf(red[2], red[3]));
    atomicMax(reinterpret_cast<unsigned int*>(out), __float_as_uint(mm));
  }
}

__global__ __launch_bounds__(256) void quant_kernel(
    const float* __restrict__ x, unsigned short* __restrict__ q,
    const float* __restrict__ amax_p, long n) {
  const float s = QMAX / fmaxf(amax_p[0], 1e-8f);
  const long stride = (long)gridDim.x * blockDim.x * 4;
  for (long i = ((long)blockIdx.x * blockDim.x + threadIdx.x) * 4; i < n; i += stride) {
    const float4 v = *reinterpret_cast<const float4*>(x + i);
    ushort4 o;
    o.x = quant_bf16(v.x, s);
    o.y = quant_bf16(v.y, s);
    o.z = quant_bf16(v.z, s);
    o.w = quant_bf16(v.w, s);
    *reinterpret_cast<ushort4*>(q + i) = o;
  }
}

__global__ __launch_bounds__(256) void quant8_kernel(
    const float* __restrict__ x, signed char* __restrict__ q,
    const float* __restrict__ amax_p, long n) {
  const float s = QMAX / fmaxf(amax_p[0], 1e-8f);
  const long stride = (long)gridDim.x * blockDim.x * 8;
  for (long i = ((long)blockIdx.x * blockDim.x + threadIdx.x) * 8; i < n; i += stride) {
    const float4 v0 = *reinterpret_cast<const float4*>(x + i);
    const float4 v1 = *reinterpret_cast<const float4*>(x + i + 4);
    uint2 o; o.x = pack4_i8(v0, s); o.y = pack4_i8(v1, s);
    *reinterpret_cast<uint2*>(q + i) = o;
  }
}

// ===========================================================================
// gemm_s8: int8 GEMM, NO residual. gbf[m][n] = bf16((i32 dot)*inv_s + b[n])
// 256x128 tile, BK=64 (16 iters), 512 thr = 8 waves (4M x 2N, 64x64 each),
// mfma_i32_16x16x64_i8.  Triple-buffered, 1 barrier/iter, counted vmcnt(3)
// (3 gload_lds/thread/tile: 2 A + 1 B), stage-at-bottom (r8/r9-validated
// ledger).  Byte-identical row geometry (64 B rows, 4x16B chunks) -> the
// verified swizzle carries over (0 conflicts).  Epilogue: two 128-row bf16
// LDS-bounce passes -> 16B-coalesced stores.
// ===========================================================================
#define BMt 256
#define BNt 128
#define BKt 64
#define NITt (H_DIM / BKt) /* 16 */

__global__ __launch_bounds__(512) void gemm_s8_kernel(
    const signed char* __restrict__ Aq8, const signed char* __restrict__ Wq8,
    const float* __restrict__ bias, const float* __restrict__ scales,
    unsigned short* __restrict__ gbf, int M) {
  // K-loop: As 3x16384 @0, Bs 3x8192 @49152 = 72 KB.
  // Epilogue bounce reuses [0..34815] as 128 rows x 136 ushorts (per pass).
  __shared__ __attribute__((aligned(16))) char SM8[73728];
  char* As = SM8;            // [3][256*64] i8
  char* Bs = SM8 + 49152;    // [3][128*64] i8

  const int nwg = (M / BMt) * 8;              // H_DIM/BNt == 8
  const int orig = blockIdx.x;
  const int cpx = nwg >> 3;
  const int wg = ((nwg & 7) == 0) ? ((orig & 7) * cpx + (orig >> 3)) : orig;
  const int bn = wg & 7, bm = wg >> 3;        // bn fast -> A panel L2 reuse
  const int m0 = bm * BMt, n0 = bn * BNt;

  const int t = threadIdx.x;
  const int lane = t & 63, wid = t >> 6;
  const int wr = wid >> 1, wc = wid & 1;      // 4x2 wave grid, 64x64 each
  const int lrow = lane & 15, lgrp = lane >> 4;

  const float amax_h = fmaxf(scales[0], 1e-8f);
  const float amax_w = fmaxf(scales[1], 1e-8f);
  const float inv_s = (amax_h * amax_w) / (QMAX * QMAX);

  // A staging: 1024 16B chunks (256 rows x 4); thread t -> chunks t, t+512.
  const int ca0 = t, ca1 = t + 512;
  const int ra0 = ca0 >> 2, ra1 = ca1 >> 2;
  const unsigned ga0 = (unsigned)ra0 * H_DIM + (unsigned)((((ca0 & 3) ^ ((ra0 >> 1) & 3))) * 16);
  const unsigned ga1 = (unsigned)ra1 * H_DIM + (unsigned)((((ca1 & 3) ^ ((ra1 >> 1) & 3))) * 16);
  // B staging: 512 chunks (128 rows x 4); thread t -> chunk t.
  const int rb = t >> 2;
  const unsigned gb = (unsigned)rb * H_DIM + (unsigned)((((t & 3) ^ ((rb >> 1) & 3))) * 16);
  const signed char* Ag = Aq8 + (size_t)m0 * H_DIM;
  const signed char* Bg = Wq8 + (size_t)n0 * H_DIM;

#define STAGE_T8(BUF, KQ)                                                      \
  { __builtin_amdgcn_global_load_lds((gmem_void*)(Ag + ga0 + (KQ)),            \
        (lds_void*)(As + (BUF)*16384 + ca0 * 16), 16, 0, 0);                   \
    __builtin_amdgcn_global_load_lds((gmem_void*)(Ag + ga1 + (KQ)),            \
        (lds_void*)(As + (BUF)*16384 + ca1 * 16), 16, 0, 0);                   \
    __builtin_amdgcn_global_load_lds((gmem_void*)(Bg + gb + (KQ)),             \
        (lds_void*)(Bs + (BUF)*8192 + t * 16), 16, 0, 0); }

  // per-thread swizzled LDS read offsets (bytes)
  int offA[4], offB[4];
#pragma unroll
  for (int i = 0; i < 4; ++i) {
    const int r = wr * 64 + i * 16 + lrow;
    offA[i] = r * 64 + ((lgrp ^ ((r >> 1) & 3)) * 16);
  }
#pragma unroll
  for (int j = 0; j < 4; ++j) {
    const int r = wc * 64 + j * 16 + lrow;
    offB[j] = r * 64 + ((lgrp ^ ((r >> 1) & 3)) * 16);
  }

  i32x4 acc[4][4];
#pragma unroll
  for (int i = 0; i < 4; i++)
#pragma unroll
    for (int j = 0; j < 4; j++)
#pragma unroll
      for (int r = 0; r < 4; r++) acc[i][j][r] = 0;

  // prologue: tiles 0 and 1 in flight (6 loads/thread)
  STAGE_T8(0, 0)
  STAGE_T8(1, BKt)

  for (int it = 0; it < NITt; ++it) {
    const int cb = it % 3;
    if (it + 1 < NITt) {
      asm volatile("s_waitcnt vmcnt(3)" ::: "memory");  // own tile-it loads done
    } else {
      asm volatile("s_waitcnt vmcnt(0)" ::: "memory");  // drain final tile
    }
    __builtin_amdgcn_s_barrier();                        // collective: tile it ready

    i32x4 af[4], bfr[4];
#pragma unroll
    for (int i = 0; i < 4; ++i)
      af[i] = *reinterpret_cast<const i32x4*>(As + cb * 16384 + offA[i]);
#pragma unroll
    for (int j = 0; j < 4; ++j)
      bfr[j] = *reinterpret_cast<const i32x4*>(Bs + cb * 8192 + offB[j]);
    __builtin_amdgcn_s_setprio(1);
#pragma unroll
    for (int i = 0; i < 4; ++i)
#pragma unroll
      for (int j = 0; j < 4; ++j)
        acc[i][j] = __builtin_amdgcn_mfma_i32_16x16x64_i8(af[i], bfr[j], acc[i][j], 0, 0, 0);
    __builtin_amdgcn_s_setprio(0);

    if (it + 2 < NITt) {
      STAGE_T8((it + 2) % 3, (unsigned)((it + 2) * BKt))  // overwrites buf[(it-1)%3]
    }
  }
#undef STAGE_T8
  __syncthreads();  // all waves done with last tile before bounce overwrites LDS

  // epilogue: two 128-row passes: bf16(acc*inv_s+bias) -> bounce -> stores
  unsigned short* SMu = reinterpret_cast<unsigned short*>(SM8);
#pragma unroll
  for (int p = 0; p < 2; ++p) {
    if ((wr >> 1) == p) {
      const int lr0 = (wr & 1) * 64;
#pragma unroll
      for (int j = 0; j < 4; ++j) {
        const int cl = wc * 64 + j * 16 + lrow;
        const float bv = bias[n0 + cl];
#pragma unroll
        for (int i = 0; i < 4; ++i) {
          const int rl0 = lr0 + i * 16 + lgrp * 4;
#pragma unroll
          for (int r = 0; r < 4; ++r)
            SMu[(rl0 + r) * 136 + cl] = f2bf_rne((float)acc[i][j][r] * inv_s + bv);
        }
      }
    }
    __syncthreads();
    {
      const int e_row = t >> 2, e_q = t & 3;  // 128 rows x 4 quarter-rows
      unsigned short* dst = gbf + (size_t)(m0 + p * 128 + e_row) * H_DIM + n0 + e_q * 32;
      const unsigned short* src = SMu + e_row * 136 + e_q * 32;
#pragma unroll
      for (int c = 0; c < 4; ++c)
        *reinterpret_cast<u16x8*>(dst + c * 8) =
            *reinterpret_cast<const u16x8*>(src + c * 8);
    }
    __syncthreads();
  }
}

// ---------------------------------------------------------------------------
// ln_resid (r6-validated): y = bf16 g + fp32 resid; LayerNorm -> fp32 out.
// ---------------------------------------------------------------------------
__global__ __launch_bounds__(256) void ln_resid_kernel(
    const unsigned short* __restrict__ gbf, const float* __restrict__ resid,
    const float* __restrict__ gamma, const float* __restrict__ beta,
    float* __restrict__ out) {
  const int rl = threadIdx.x >> 7;
  const int c0 = (threadIdx.x & 127) * 8;
  const size_t base = ((size_t)blockIdx.x * 2 + rl) * H_DIM + c0;

  const u16x8 g = *reinterpret_cast<const u16x8*>(gbf + base);
  const float4 rA = *reinterpret_cast<const float4*>(resid + base);
  const float4 rB = *reinterpret_cast<const float4*>(resid + base + 4);
  float v[8];
  v[0] = bf2f(g[0]) + rA.x; v[1] = bf2f(g[1]) + rA.y;
  v[2] = bf2f(g[2]) + rA.z; v[3] = bf2f(g[3]) + rA.w;
  v[4] = bf2f(g[4]) + rB.x; v[5] = bf2f(g[5]) + rB.y;
  v[6] = bf2f(g[6]) + rB.z; v[7] = bf2f(g[7]) + rB.w;

  float s = 0.f, ss = 0.f;
#pragma unroll
  for (int k = 0; k < 8; ++k) { s += v[k]; ss += v[k] * v[k]; }
#pragma unroll
  for (int off = 32; off > 0; off >>= 1) {
    s += __shfl_down(s, off);
    ss += __shfl_down(ss, off);
  }
  __shared__ float red[4][2];
  const int lane = threadIdx.x & 63, w = threadIdx.x >> 6;
  if (lane == 0) { red[w][0] = s; red[w][1] = ss; }
  __syncthreads();
  const int wp = rl * 2;
  const float stot = red[wp][0] + red[wp + 1][0];
  const float sstot = red[wp][1] + red[wp + 1][1];
  const float mu = stot * (1.0f / H_DIM);
  const float var = fmaxf(sstot * (1.0f / H_DIM) - mu * mu, 0.f);
  const float rs = rsqrtf(var + 1e-12f);

  const float4 gA = *reinterpret_cast<const float4*>(gamma + c0);
  const float4 gB = *reinterpret_cast<const float4*>(gamma + c0 + 4);
  const float4 bA = *reinterpret_cast<const float4*>(beta + c0);
  const float4 bB = *reinterpret_cast<const float4*>(beta + c0 + 4);
  float4 oA, oB;
  oA.x = (v[0] - mu) * rs * gA.x + bA.x;
  oA.y = (v[1] - mu) * rs * gA.y + bA.y;
  oA.z = (v[2] - mu) * rs * gA.z + bA.z;
  oA.w = (v[3] - mu) * rs * gA.w + bA.w;
  oB.x = (v[4] - mu) * rs * gB.x + bB.x;
  oB.y = (v[5] - mu) * rs * gB.y + bB.y;
  oB.z = (v[6] - mu) * rs * gB.z + bB.z;
  oB.w = (v[7] - mu) * rs * gB.w + bB.w;
  *reinterpret_cast<float4*>(out + base) = oA;
  *reinterpret_cast<float4*>(out + base + 4) = oB;
}

// ===========================================================================
// Tier-3 fallback (round-1 validated): fused-quant bf16 GEMM + LN.
// ===========================================================================
#define BM 128
#define BN 128
#define BK 32

__global__ __launch_bounds__(256, 2) void gemm_fused_kernel(
    const float* __restrict__ A, const unsigned short* __restrict__ Wq,
    const float* __restrict__ bias, const float* __restrict__ resid,
    const float* __restrict__ scales, float* __restrict__ out, int M) {
  __shared__ unsigned short Asf[BM][40];
  __shared__ unsigned short Bsf[BN][40];
  const int nbm = M / BM;
  const int bm = blockIdx.x % nbm, bn = blockIdx.x / nbm;
  const int m0 = bm * BM, n0 = bn * BN;
  const int t = threadIdx.x;
  const int lane = t & 63, wid = t >> 6;
  const int wr = wid >> 1, wc = wid & 1;
  const int lrow = lane & 15, lgrp = lane >> 4;
  const float amax_h = fmaxf(scales[0], 1e-8f);
  const float amax_w = fmaxf(scales[1], 1e-8f);
  const float sh = QMAX / amax_h;
  const float inv_s = (amax_h * amax_w) / (QMAX * QMAX);
  f32x4 acc[4][4];
#pragma unroll
  for (int i = 0; i < 4; i++)
#pragma unroll
    for (int j = 0; j < 4; j++)
#pragma unroll
      for (int r = 0; r < 4; r++) acc[i][j][r] = 0.f;
  for (int k0 = 0; k0 < H_DIM; k0 += BK) {
#pragma unroll
    for (int j = 0; j < 4; ++j) {
      const int f = j * 256 + t;
      const int r = f >> 3, c4 = f & 7;
      const float4 v = *reinterpret_cast<const float4*>(A + (size_t)(m0 + r) * H_DIM + k0 + c4 * 4);
      ushort4 q;
      q.x = quant_bf16(v.x, sh); q.y = quant_bf16(v.y, sh);
      q.z = quant_bf16(v.z, sh); q.w = quant_bf16(v.w, sh);
      *reinterpret_cast<ushort4*>(&Asf[r][c4 * 4]) = q;
    }
#pragma unroll
    for (int j = 0; j < 2; ++j) {
      const int f = j * 256 + t;
      const int r = f >> 2, cb = f & 3;
      const uint4 v = *reinterpret_cast<const uint4*>(Wq + (size_t)(n0 + r) * H_DIM + k0 + cb * 8);
      *reinterpret_cast<uint4*>(&Bsf[r][cb * 8]) = v;
    }
    __syncthreads();
    bf16x8 af[4], bfr[4];
#pragma unroll
    for (int i = 0; i < 4; i++)
      af[i] = *reinterpret_cast<const bf16x8*>(&Asf[wr * 64 + i * 16 + lrow][lgrp * 8]);
#pragma unroll
    for (int j = 0; j < 4; j++)
      bfr[j] = *reinterpret_cast<const bf16x8*>(&Bsf[wc * 64 + j * 16 + lrow][lgrp * 8]);
#pragma unroll
    for (int i = 0; i < 4; i++)
#pragma unroll
      for (int j = 0; j < 4; j++)
        acc[i][j] = __builtin_amdgcn_mfma_f32_16x16x32_bf16(af[i], bfr[j], acc[i][j], 0, 0, 0);
    __syncthreads();
  }
#pragma unroll
  for (int j = 0; j < 4; j++) {
    const int col = n0 + wc * 64 + j * 16 + lrow;
    const float bv = bias[col];
#pragma unroll
    for (int i = 0; i < 4; i++) {
      const int row0 = m0 + wr * 64 + i * 16 + lgrp * 4;
#pragma unroll
      for (int r = 0; r < 4; r++) {
        const size_t off = (size_t)(row0 + r) * H_DIM + col;
        out[off] = acc[i][j][r] * inv_s + bv + resid[off];
      }
    }
  }
}

__global__ __launch_bounds__(256) void ln_kernel(
    float* __restrict__ y, const float* __restrict__ gamma,
    const float* __restrict__ beta) {
  const size_t base = (size_t)blockIdx.x * H_DIM + threadIdx.x * 4;
  const float4 v = *reinterpret_cast<const float4*>(y + base);
  float s = v.x + v.y + v.z + v.w;
  float ss = v.x * v.x + v.y * v.y + v.z * v.z + v.w * v.w;
#pragma unroll
  for (int off = 32; off > 0; off >>= 1) {
    s += __shfl_down(s, off);
    ss += __shfl_down(ss, off);
  }
  __shared__ float red[8];
  const int lane = threadIdx.x & 63, w = threadIdx.x >> 6;
  if (lane == 0) { red[w] = s; red[4 + w] = ss; }
  __syncthreads();
  const float stot = red[0] + red[1] + red[2] + red[3];
  const float sstot = red[4] + red[5] + red[6] + red[7];
  const float mu = stot * (1.0f / H_DIM);
  const float var = fmaxf(sstot * (1.0f / H_DIM) - mu * mu, 0.f);
  const float rs = rsqrtf(var + 1e-12f);
  const float4 g = *reinterpret_cast<const float4*>(gamma + threadIdx.x * 4);
  const float4 b = *reinterpret_cast<const float4*>(beta + threadIdx.x * 4);
  float4 o;
  o.x = (v.x - mu) * rs * g.x + b.x;
  o.y = (v.y - mu) * rs * g.y + b.y;
  o.z = (v.z - mu) * rs * g.z + b.z;
  o.w = (v.w - mu) * rs * g.w + b.w;
  *reinterpret_cast<float4*>(y + base) = o;
}

extern "C" void kernel_launch(void* const* d_in, const int* in_sizes, int n_in,
                              void* d_out, int out_size, void* d_ws, size_t ws_size,
                              hipStream_t stream) {
  const float* hidden = (const float*)d_in[0];
  const float* resid  = (const float*)d_in[1];
  const float* weight = (const float*)d_in[2];
  const float* bias   = (const float*)d_in[3];
  const float* gamma  = (const float*)d_in[4];
  const float* beta   = (const float*)d_in[5];
  float* out = (float*)d_out;

  const long nh = (long)in_sizes[0];   // B*S*H
  const int M = (int)(nh / H_DIM);     // 32768
  const long nw = (long)H_DIM * H_DIM;

  float* scales = (float*)d_ws;
  char* base = (char*)d_ws + 256;
  signed char* Wq8 = (signed char*)base;                    // 1 MB
  signed char* Aq8 = (signed char*)(base + nw);             // nh bytes
  unsigned short* gbf = (unsigned short*)(base + nw + nh);  // nh*2 bytes
  const size_t need1 = 256 + (size_t)nw + (size_t)nh * 3;
  const size_t need3 = 256 + (size_t)nw * 2;

  hipMemsetAsync(d_ws, 0, 8, stream);

  if (ws_size >= need1 && (M % BMt) == 0 && (nh % 8) == 0) {
    // ---- main i8 path (r9-validated front-end, 256x128 GEMM) ----
    absmax_clip_kernel<<<2048, 256, 0, stream>>>(hidden, nh, scales + 0);
    absmax_clip_kernel<<<256, 256, 0, stream>>>(weight, nw, scales + 1);
    quant8_kernel<<<512, 256, 0, stream>>>(weight, Wq8, scales + 1, nw);
    quant8_kernel<<<2048, 256, 0, stream>>>(hidden, Aq8, scales + 0, nh);
    gemm_s8_kernel<<<(M / BMt) * (H_DIM / BNt), 512, 0, stream>>>(
        Aq8, Wq8, bias, scales, gbf, M);
    ln_resid_kernel<<<M / 2, 256, 0, stream>>>(gbf, resid, gamma, beta, out);
  } else if (ws_size >= need3 && (M % BM) == 0) {
    // ---- tier-3 bf16 fallback ----
    unsigned short* Wqf = (unsigned short*)base;
    absmax_clip_kernel<<<2048, 256, 0, stream>>>(hidden, nh, scales + 0);
    absmax_clip_kernel<<<256, 256, 0, stream>>>(weight, nw, scales + 1);
    quant_kernel<<<1024, 256, 0, stream>>>(weight, Wqf, scales + 1, nw);
    gemm_fused_kernel<<<(M / BM) * (H_DIM / BN), 256, 0, stream>>>(
        hidden, Wqf, bias, resid, scales, out, M);
    ln_kernel<<<M, 256, 0, stream>>>(out, gamma, beta);
  }
}

// Round 12
// 199.198 us; speedup vs baseline: 1.3092x; 1.0173x over previous
//
#include <hip/hip_runtime.h>
#include <hip/hip_bf16.h>
#include <stdint.h>

#define H_DIM 1024
#define QMAX 127.0f
#define CLIP 2.5f

typedef __attribute__((ext_vector_type(4))) float f32x4;
typedef __attribute__((ext_vector_type(4))) int i32x4;
typedef __attribute__((ext_vector_type(8))) short bf16x8;
typedef __attribute__((ext_vector_type(8))) unsigned short u16x8;
typedef __attribute__((address_space(3))) void lds_void;
typedef const __attribute__((address_space(1))) void gmem_void;

__device__ __forceinline__ unsigned short quant_bf16(float x, float s) {
  const float q = rintf(fminf(fmaxf(x, -CLIP), CLIP) * s);
  return (unsigned short)(__float_as_uint(q) >> 16);
}

__device__ __forceinline__ int quant_i8(float x, float s) {
  return (int)rintf(fminf(fmaxf(x, -CLIP), CLIP) * s);  // in [-127,127]
}

__device__ __forceinline__ unsigned short f2bf_rne(float f) {
  const unsigned u = __float_as_uint(f);
  return (unsigned short)((u + 0x7FFFu + ((u >> 16) & 1u)) >> 16);
}

__device__ __forceinline__ float bf2f(unsigned short u) {
  return __uint_as_float((unsigned)u << 16);
}

__device__ __forceinline__ unsigned pack4_i8(float4 v, float s) {
  return ((unsigned)(unsigned char)(signed char)quant_i8(v.x, s)) |
         ((unsigned)(unsigned char)(signed char)quant_i8(v.y, s) << 8) |
         ((unsigned)(unsigned char)(signed char)quant_i8(v.z, s) << 16) |
         ((unsigned)(unsigned char)(signed char)quant_i8(v.w, s) << 24);
}

// ---------------------------------------------------------------------------
// absmax of clip(x,-CLIP,CLIP) (n%4==0), atomicMax into *out (pre-zeroed).
// ---------------------------------------------------------------------------
__global__ __launch_bounds__(256) void absmax_clip_kernel(
    const float* __restrict__ x, long n, float* __restrict__ out) {
  float m = 0.f;
  const long stride = (long)gridDim.x * blockDim.x * 4;
  for (long i = ((long)blockIdx.x * blockDim.x + threadIdx.x) * 4; i < n; i += stride) {
    const float4 v = *reinterpret_cast<const float4*>(x + i);
    m = fmaxf(m, fmaxf(fmaxf(fabsf(v.x), fabsf(v.y)), fmaxf(fabsf(v.z), fabsf(v.w))));
  }
  m = fminf(m, CLIP);
#pragma unroll
  for (int off = 32; off > 0; off >>= 1) m = fmaxf(m, __shfl_down(m, off));
  __shared__ float red[4];
  const int lane = threadIdx.x & 63, w = threadIdx.x >> 6;
  if (lane == 0) red[w] = m;
  __syncthreads();
  if (threadIdx.x == 0) {
    const float mm = fmaxf(fmaxf(red[0], red[1]), fmaxf(red[2], red[3]));
    atomicMax(reinterpret_cast<unsigned int*>(out), __float_as_uint(mm));
  }
}

__global__ __launch_bounds__(256) void quant_kernel(
    const float* __restrict__ x, unsigned short* __restrict__ q,
    const float* __restrict__ amax_p, long n) {
  const float s = QMAX / fmaxf(amax_p[0], 1e-8f);
  const long stride = (long)gridDim.x * blockDim.x * 4;
  for (long i = ((long)blockIdx.x * blockDim.x + threadIdx.x) * 4; i < n; i += stride) {
    const float4 v = *reinterpret_cast<const float4*>(x + i);
    ushort4 o;
    o.x = quant_bf16(v.x, s);
    o.y = quant_bf16(v.y, s);
    o.z = quant_bf16(v.z, s);
    o.w = quant_bf16(v.w, s);
    *reinterpret_cast<ushort4*>(q + i) = o;
  }
}

__global__ __launch_bounds__(256) void quant8_kernel(
    const float* __restrict__ x, signed char* __restrict__ q,
    const float* __restrict__ amax_p, long n) {
  const float s = QMAX / fmaxf(amax_p[0], 1e-8f);
  const long stride = (long)gridDim.x * blockDim.x * 8;
  for (long i = ((long)blockIdx.x * blockDim.x + threadIdx.x) * 8; i < n; i += stride) {
    const float4 v0 = *reinterpret_cast<const float4*>(x + i);
    const float4 v1 = *reinterpret_cast<const float4*>(x + i + 4);
    uint2 o; o.x = pack4_i8(v0, s); o.y = pack4_i8(v1, s);
    *reinterpret_cast<uint2*>(q + i) = o;
  }
}

// ===========================================================================
// gemm_s8: int8 GEMM, NO residual. gbf[m][n] = bf16((i32 dot)*inv_s + b[n])
// 128x128 tile, BK=64 (16 iters), 256 thr (4 waves 2x2), mfma_i32_16x16x64_i8.
// K-loop: FIVE-buffered (depth-3 prefetch), 1 barrier/iter, counted vmcnt:
//   [iter it] vmcnt(4*(min(it+3,NIT-1)-it)) ; s_barrier ;
//             ds_read buf[it%5] + MFMA ; stage buf[(it+4)%5] (tile it+4)
// Each tile has ~3 iterations (~1200+ cyc) to land -> covers L2/HBM latency.
// Ledger: (RAW) vmcnt retires own-wave tile-it loads, barrier collectivizes.
// (WAR) stage of it+4 overwrites buf[(it-1)%5]; all waves retired tile-(it-1)
// ds_reads before iter-it's barrier (lgkmcnt forced by MFMA use); stage is
// after that barrier.  Swizzle r9-verified (0 conflicts).  LDS 80 KB ->
// 2 blocks/CU.  Epilogue: bf16 LDS-bounce -> 16B-coalesced stores.
// ===========================================================================
#define BMs 128
#define BNs 128
#define BKs8 64
#define NIT8 (H_DIM / BKs8) /* 16 */

__global__ __launch_bounds__(256) void gemm_s8_kernel(
    const signed char* __restrict__ Aq8, const signed char* __restrict__ Wq8,
    const float* __restrict__ bias, const float* __restrict__ scales,
    unsigned short* __restrict__ gbf, int M) {
  // K-loop: As 5x8192 @0, Bs 5x8192 @40960 = 80 KB.
  // Epilogue bounce reuses [0..34815] as 128 rows x 136 ushorts.
  __shared__ __attribute__((aligned(16))) char SM8[81920];
  char* As = SM8;            // [5][128*64] i8
  char* Bs = SM8 + 40960;    // [5][128*64] i8

  const int nwg = (M / BMs) * 8;
  const int orig = blockIdx.x;
  const int cpx = nwg >> 3;
  const int wg = ((nwg & 7) == 0) ? ((orig & 7) * cpx + (orig >> 3)) : orig;
  const int bn = wg & 7, bm = wg >> 3;      // bn fast -> A panel L2 reuse
  const int m0 = bm * BMs, n0 = bn * BNs;

  const int t = threadIdx.x;
  const int lane = t & 63, wid = t >> 6;
  const int wr = wid >> 1, wc = wid & 1;
  const int lrow = lane & 15, lgrp = lane >> 4;

  const float amax_h = fmaxf(scales[0], 1e-8f);
  const float amax_w = fmaxf(scales[1], 1e-8f);
  const float inv_s = (amax_h * amax_w) / (QMAX * QMAX);

  // staging: 512 16B chunks per 128x64 tile; chunk c -> row c>>2, grp c&3;
  // global source col-group inverse-swizzled (byte offsets).
  const int c0 = t, c1 = t + 256;
  const int r0 = c0 >> 2, r1 = c1 >> 2;
  const unsigned g0 = (unsigned)r0 * H_DIM + (unsigned)((((c0 & 3) ^ ((r0 >> 1) & 3))) * 16);
  const unsigned g1 = (unsigned)r1 * H_DIM + (unsigned)((((c1 & 3) ^ ((r1 >> 1) & 3))) * 16);
  const signed char* Ag = Aq8 + (size_t)m0 * H_DIM;
  const signed char* Bg = Wq8 + (size_t)n0 * H_DIM;

#define STAGE_T8(BUF, KQ)                                                      \
  { __builtin_amdgcn_global_load_lds((gmem_void*)(Ag + g0 + (KQ)),             \
        (lds_void*)(As + (BUF)*8192 + c0 * 16), 16, 0, 0);                     \
    __builtin_amdgcn_global_load_lds((gmem_void*)(Ag + g1 + (KQ)),             \
        (lds_void*)(As + (BUF)*8192 + c1 * 16), 16, 0, 0);                     \
    __builtin_amdgcn_global_load_lds((gmem_void*)(Bg + g0 + (KQ)),             \
        (lds_void*)(Bs + (BUF)*8192 + c0 * 16), 16, 0, 0);                     \
    __builtin_amdgcn_global_load_lds((gmem_void*)(Bg + g1 + (KQ)),             \
        (lds_void*)(Bs + (BUF)*8192 + c1 * 16), 16, 0, 0); }

  int offA[4], offB[4];
#pragma unroll
  for (int i = 0; i < 4; ++i) {
    const int r = wr * 64 + i * 16 + lrow;
    offA[i] = r * 64 + ((lgrp ^ ((r >> 1) & 3)) * 16);
  }
#pragma unroll
  for (int j = 0; j < 4; ++j) {
    const int r = wc * 64 + j * 16 + lrow;
    offB[j] = r * 64 + ((lgrp ^ ((r >> 1) & 3)) * 16);
  }

  i32x4 acc[4][4];
#pragma unroll
  for (int i = 0; i < 4; i++)
#pragma unroll
    for (int j = 0; j < 4; j++)
#pragma unroll
      for (int r = 0; r < 4; r++) acc[i][j][r] = 0;

  // prologue: tiles 0..3 in flight (16 loads/thread)
  STAGE_T8(0, 0)
  STAGE_T8(1, BKs8)
  STAGE_T8(2, 2 * BKs8)
  STAGE_T8(3, 3 * BKs8)

  for (int it = 0; it < NIT8; ++it) {
    const int cb = it % 5;
    // allowed outstanding = 4 * (min(it+3, NIT-1) - it)
    if (it <= NIT8 - 4) {
      asm volatile("s_waitcnt vmcnt(12)" ::: "memory");
    } else if (it == NIT8 - 3) {
      asm volatile("s_waitcnt vmcnt(8)" ::: "memory");
    } else if (it == NIT8 - 2) {
      asm volatile("s_waitcnt vmcnt(4)" ::: "memory");
    } else {
      asm volatile("s_waitcnt vmcnt(0)" ::: "memory");
    }
    __builtin_amdgcn_s_barrier();  // collective: tile it ready

    i32x4 af[4], bfr[4];
#pragma unroll
    for (int i = 0; i < 4; ++i)
      af[i] = *reinterpret_cast<const i32x4*>(As + cb * 8192 + offA[i]);
#pragma unroll
    for (int j = 0; j < 4; ++j)
      bfr[j] = *reinterpret_cast<const i32x4*>(Bs + cb * 8192 + offB[j]);
    __builtin_amdgcn_s_setprio(1);
#pragma unroll
    for (int i = 0; i < 4; ++i)
#pragma unroll
      for (int j = 0; j < 4; ++j)
        acc[i][j] = __builtin_amdgcn_mfma_i32_16x16x64_i8(af[i], bfr[j], acc[i][j], 0, 0, 0);
    __builtin_amdgcn_s_setprio(0);

    if (it + 4 < NIT8) {
      STAGE_T8((it + 4) % 5, (unsigned)((it + 4) * BKs8))  // overwrites buf[(it-1)%5]
    }
  }
#undef STAGE_T8
  __syncthreads();  // all waves done with last tile before bounce overwrites LDS

  // epilogue: g = bf16((float)acc*inv_s + bias) -> LDS bounce -> coalesced
  unsigned short* SMu = reinterpret_cast<unsigned short*>(SM8);
#pragma unroll
  for (int j = 0; j < 4; ++j) {
    const int cl = wc * 64 + j * 16 + lrow;
    const float bv = bias[n0 + cl];
#pragma unroll
    for (int i = 0; i < 4; ++i) {
      const int rl0 = wr * 64 + i * 16 + lgrp * 4;
#pragma unroll
      for (int r = 0; r < 4; ++r)
        SMu[(rl0 + r) * 136 + cl] = f2bf_rne((float)acc[i][j][r] * inv_s + bv);
    }
  }
  __syncthreads();
  {
    const int e_row = t >> 1, e_half = t & 1;
    unsigned short* dst = gbf + (size_t)(m0 + e_row) * H_DIM + n0 + e_half * 64;
    const unsigned short* src = SMu + e_row * 136 + e_half * 64;
#pragma unroll
    for (int c = 0; c < 8; ++c)
      *reinterpret_cast<u16x8*>(dst + c * 8) =
          *reinterpret_cast<const u16x8*>(src + c * 8);
  }
}

// ---------------------------------------------------------------------------
// ln_resid (r6-validated): y = bf16 g + fp32 resid; LayerNorm -> fp32 out.
// ---------------------------------------------------------------------------
__global__ __launch_bounds__(256) void ln_resid_kernel(
    const unsigned short* __restrict__ gbf, const float* __restrict__ resid,
    const float* __restrict__ gamma, const float* __restrict__ beta,
    float* __restrict__ out) {
  const int rl = threadIdx.x >> 7;
  const int c0 = (threadIdx.x & 127) * 8;
  const size_t base = ((size_t)blockIdx.x * 2 + rl) * H_DIM + c0;

  const u16x8 g = *reinterpret_cast<const u16x8*>(gbf + base);
  const float4 rA = *reinterpret_cast<const float4*>(resid + base);
  const float4 rB = *reinterpret_cast<const float4*>(resid + base + 4);
  float v[8];
  v[0] = bf2f(g[0]) + rA.x; v[1] = bf2f(g[1]) + rA.y;
  v[2] = bf2f(g[2]) + rA.z; v[3] = bf2f(g[3]) + rA.w;
  v[4] = bf2f(g[4]) + rB.x; v[5] = bf2f(g[5]) + rB.y;
  v[6] = bf2f(g[6]) + rB.z; v[7] = bf2f(g[7]) + rB.w;

  float s = 0.f, ss = 0.f;
#pragma unroll
  for (int k = 0; k < 8; ++k) { s += v[k]; ss += v[k] * v[k]; }
#pragma unroll
  for (int off = 32; off > 0; off >>= 1) {
    s += __shfl_down(s, off);
    ss += __shfl_down(ss, off);
  }
  __shared__ float red[4][2];
  const int lane = threadIdx.x & 63, w = threadIdx.x >> 6;
  if (lane == 0) { red[w][0] = s; red[w][1] = ss; }
  __syncthreads();
  const int wp = rl * 2;
  const float stot = red[wp][0] + red[wp + 1][0];
  const float sstot = red[wp][1] + red[wp + 1][1];
  const float mu = stot * (1.0f / H_DIM);
  const float var = fmaxf(sstot * (1.0f / H_DIM) - mu * mu, 0.f);
  const float rs = rsqrtf(var + 1e-12f);

  const float4 gA = *reinterpret_cast<const float4*>(gamma + c0);
  const float4 gB = *reinterpret_cast<const float4*>(gamma + c0 + 4);
  const float4 bA = *reinterpret_cast<const float4*>(beta + c0);
  const float4 bB = *reinterpret_cast<const float4*>(beta + c0 + 4);
  float4 oA, oB;
  oA.x = (v[0] - mu) * rs * gA.x + bA.x;
  oA.y = (v[1] - mu) * rs * gA.y + bA.y;
  oA.z = (v[2] - mu) * rs * gA.z + bA.z;
  oA.w = (v[3] - mu) * rs * gA.w + bA.w;
  oB.x = (v[4] - mu) * rs * gB.x + bB.x;
  oB.y = (v[5] - mu) * rs * gB.y + bB.y;
  oB.z = (v[6] - mu) * rs * gB.z + bB.z;
  oB.w = (v[7] - mu) * rs * gB.w + bB.w;
  *reinterpret_cast<float4*>(out + base) = oA;
  *reinterpret_cast<float4*>(out + base + 4) = oB;
}

// ===========================================================================
// Tier-3 fallback (round-1 validated): fused-quant bf16 GEMM + LN.
// ===========================================================================
#define BM 128
#define BN 128
#define BK 32

__global__ __launch_bounds__(256, 2) void gemm_fused_kernel(
    const float* __restrict__ A, const unsigned short* __restrict__ Wq,
    const float* __restrict__ bias, const float* __restrict__ resid,
    const float* __restrict__ scales, float* __restrict__ out, int M) {
  __shared__ unsigned short Asf[BM][40];
  __shared__ unsigned short Bsf[BN][40];
  const int nbm = M / BM;
  const int bm = blockIdx.x % nbm, bn = blockIdx.x / nbm;
  const int m0 = bm * BM, n0 = bn * BN;
  const int t = threadIdx.x;
  const int lane = t & 63, wid = t >> 6;
  const int wr = wid >> 1, wc = wid & 1;
  const int lrow = lane & 15, lgrp = lane >> 4;
  const float amax_h = fmaxf(scales[0], 1e-8f);
  const float amax_w = fmaxf(scales[1], 1e-8f);
  const float sh = QMAX / amax_h;
  const float inv_s = (amax_h * amax_w) / (QMAX * QMAX);
  f32x4 acc[4][4];
#pragma unroll
  for (int i = 0; i < 4; i++)
#pragma unroll
    for (int j = 0; j < 4; j++)
#pragma unroll
      for (int r = 0; r < 4; r++) acc[i][j][r] = 0.f;
  for (int k0 = 0; k0 < H_DIM; k0 += BK) {
#pragma unroll
    for (int j = 0; j < 4; ++j) {
      const int f = j * 256 + t;
      const int r = f >> 3, c4 = f & 7;
      const float4 v = *reinterpret_cast<const float4*>(A + (size_t)(m0 + r) * H_DIM + k0 + c4 * 4);
      ushort4 q;
      q.x = quant_bf16(v.x, sh); q.y = quant_bf16(v.y, sh);
      q.z = quant_bf16(v.z, sh); q.w = quant_bf16(v.w, sh);
      *reinterpret_cast<ushort4*>(&Asf[r][c4 * 4]) = q;
    }
#pragma unroll
    for (int j = 0; j < 2; ++j) {
      const int f = j * 256 + t;
      const int r = f >> 2, cb = f & 3;
      const uint4 v = *reinterpret_cast<const uint4*>(Wq + (size_t)(n0 + r) * H_DIM + k0 + cb * 8);
      *reinterpret_cast<uint4*>(&Bsf[r][cb * 8]) = v;
    }
    __syncthreads();
    bf16x8 af[4], bfr[4];
#pragma unroll
    for (int i = 0; i < 4; i++)
      af[i] = *reinterpret_cast<const bf16x8*>(&Asf[wr * 64 + i * 16 + lrow][lgrp * 8]);
#pragma unroll
    for (int j = 0; j < 4; j++)
      bfr[j] = *reinterpret_cast<const bf16x8*>(&Bsf[wc * 64 + j * 16 + lrow][lgrp * 8]);
#pragma unroll
    for (int i = 0; i < 4; i++)
#pragma unroll
      for (int j = 0; j < 4; j++)
        acc[i][j] = __builtin_amdgcn_mfma_f32_16x16x32_bf16(af[i], bfr[j], acc[i][j], 0, 0, 0);
    __syncthreads();
  }
#pragma unroll
  for (int j = 0; j < 4; j++) {
    const int col = n0 + wc * 64 + j * 16 + lrow;
    const float bv = bias[col];
#pragma unroll
    for (int i = 0; i < 4; i++) {
      const int row0 = m0 + wr * 64 + i * 16 + lgrp * 4;
#pragma unroll
      for (int r = 0; r < 4; r++) {
        const size_t off = (size_t)(row0 + r) * H_DIM + col;
        out[off] = acc[i][j][r] * inv_s + bv + resid[off];
      }
    }
  }
}

__global__ __launch_bounds__(256) void ln_kernel(
    float* __restrict__ y, const float* __restrict__ gamma,
    const float* __restrict__ beta) {
  const size_t base = (size_t)blockIdx.x * H_DIM + threadIdx.x * 4;
  const float4 v = *reinterpret_cast<const float4*>(y + base);
  float s = v.x + v.y + v.z + v.w;
  float ss = v.x * v.x + v.y * v.y + v.z * v.z + v.w * v.w;
#pragma unroll
  for (int off = 32; off > 0; off >>= 1) {
    s += __shfl_down(s, off);
    ss += __shfl_down(ss, off);
  }
  __shared__ float red[8];
  const int lane = threadIdx.x & 63, w = threadIdx.x >> 6;
  if (lane == 0) { red[w] = s; red[4 + w] = ss; }
  __syncthreads();
  const float stot = red[0] + red[1] + red[2] + red[3];
  const float sstot = red[4] + red[5] + red[6] + red[7];
  const float mu = stot * (1.0f / H_DIM);
  const float var = fmaxf(sstot * (1.0f / H_DIM) - mu * mu, 0.f);
  const float rs = rsqrtf(var + 1e-12f);
  const float4 g = *reinterpret_cast<const float4*>(gamma + threadIdx.x * 4);
  const float4 b = *reinterpret_cast<const float4*>(beta + threadIdx.x * 4);
  float4 o;
  o.x = (v.x - mu) * rs * g.x + b.x;
  o.y = (v.y - mu) * rs * g.y + b.y;
  o.z = (v.z - mu) * rs * g.z + b.z;
  o.w = (v.w - mu) * rs * g.w + b.w;
  *reinterpret_cast<float4*>(y + base) = o;
}

extern "C" void kernel_launch(void* const* d_in, const int* in_sizes, int n_in,
                              void* d_out, int out_size, void* d_ws, size_t ws_size,
                              hipStream_t stream) {
  const float* hidden = (const float*)d_in[0];
  const float* resid  = (const float*)d_in[1];
  const float* weight = (const float*)d_in[2];
  const float* bias   = (const float*)d_in[3];
  const float* gamma  = (const float*)d_in[4];
  const float* beta   = (const float*)d_in[5];
  float* out = (float*)d_out;

  const long nh = (long)in_sizes[0];   // B*S*H
  const int M = (int)(nh / H_DIM);     // 32768
  const long nw = (long)H_DIM * H_DIM;

  float* scales = (float*)d_ws;
  char* base = (char*)d_ws + 256;
  signed char* Wq8 = (signed char*)base;                    // 1 MB
  signed char* Aq8 = (signed char*)(base + nw);             // nh bytes
  unsigned short* gbf = (unsigned short*)(base + nw + nh);  // nh*2 bytes
  const size_t need1 = 256 + (size_t)nw + (size_t)nh * 3;
  const size_t need3 = 256 + (size_t)nw * 2;

  hipMemsetAsync(d_ws, 0, 8, stream);

  if (ws_size >= need1 && (M % BMs) == 0 && (M % 2) == 0 && (nh % 8) == 0) {
    // ---- main i8 path (r9-validated front-end, 5-buffer GEMM) ----
    absmax_clip_kernel<<<2048, 256, 0, stream>>>(hidden, nh, scales + 0);
    absmax_clip_kernel<<<256, 256, 0, stream>>>(weight, nw, scales + 1);
    quant8_kernel<<<512, 256, 0, stream>>>(weight, Wq8, scales + 1, nw);
    quant8_kernel<<<2048, 256, 0, stream>>>(hidden, Aq8, scales + 0, nh);
    gemm_s8_kernel<<<(M / BMs) * (H_DIM / BNs), 256, 0, stream>>>(
        Aq8, Wq8, bias, scales, gbf, M);
    ln_resid_kernel<<<M / 2, 256, 0, stream>>>(gbf, resid, gamma, beta, out);
  } else if (ws_size >= need3 && (M % BM) == 0) {
    // ---- tier-3 bf16 fallback ----
    unsigned short* Wqf = (unsigned short*)base;
    absmax_clip_kernel<<<2048, 256, 0, stream>>>(hidden, nh, scales + 0);
    absmax_clip_kernel<<<256, 256, 0, stream>>>(weight, nw, scales + 1);
    quant_kernel<<<1024, 256, 0, stream>>>(weight, Wqf, scales + 1, nw);
    gemm_fused_kernel<<<(M / BM) * (H_DIM / BN), 256, 0, stream>>>(
        hidden, Wqf, bias, resid, scales, out, M);
    ln_kernel<<<M, 256, 0, stream>>>(out, gamma, beta);
  }
}

// Round 13
// 196.891 us; speedup vs baseline: 1.3246x; 1.0117x over previous
//
#include <hip/hip_runtime.h>
#include <hip/hip_bf16.h>
#include <stdint.h>

#define H_DIM 1024
#define QMAX 127.0f
#define CLIP 2.5f

typedef __attribute__((ext_vector_type(4))) float f32x4;
typedef __attribute__((ext_vector_type(4))) int i32x4;
typedef __attribute__((ext_vector_type(8))) short bf16x8;
typedef __attribute__((ext_vector_type(8))) unsigned short u16x8;
typedef __attribute__((address_space(3))) void lds_void;
typedef const __attribute__((address_space(1))) void gmem_void;

__device__ __forceinline__ unsigned short quant_bf16(float x, float s) {
  const float q = rintf(fminf(fmaxf(x, -CLIP), CLIP) * s);
  return (unsigned short)(__float_as_uint(q) >> 16);
}

__device__ __forceinline__ int quant_i8(float x, float s) {
  return (int)rintf(fminf(fmaxf(x, -CLIP), CLIP) * s);  // in [-127,127]
}

__device__ __forceinline__ unsigned short f2bf_rne(float f) {
  const unsigned u = __float_as_uint(f);
  return (unsigned short)((u + 0x7FFFu + ((u >> 16) & 1u)) >> 16);
}

__device__ __forceinline__ float bf2f(unsigned short u) {
  return __uint_as_float((unsigned)u << 16);
}

__device__ __forceinline__ unsigned pack4_i8(float4 v, float s) {
  return ((unsigned)(unsigned char)(signed char)quant_i8(v.x, s)) |
         ((unsigned)(unsigned char)(signed char)quant_i8(v.y, s) << 8) |
         ((unsigned)(unsigned char)(signed char)quant_i8(v.z, s) << 16) |
         ((unsigned)(unsigned char)(signed char)quant_i8(v.w, s) << 24);
}

// ---------------------------------------------------------------------------
// absmax of clip(x,-CLIP,CLIP) (n%4==0), atomicMax into *out (pre-zeroed).
// ---------------------------------------------------------------------------
__global__ __launch_bounds__(256) void absmax_clip_kernel(
    const float* __restrict__ x, long n, float* __restrict__ out) {
  float m = 0.f;
  const long stride = (long)gridDim.x * blockDim.x * 4;
  for (long i = ((long)blockIdx.x * blockDim.x + threadIdx.x) * 4; i < n; i += stride) {
    const float4 v = *reinterpret_cast<const float4*>(x + i);
    m = fmaxf(m, fmaxf(fmaxf(fabsf(v.x), fabsf(v.y)), fmaxf(fabsf(v.z), fabsf(v.w))));
  }
  m = fminf(m, CLIP);
#pragma unroll
  for (int off = 32; off > 0; off >>= 1) m = fmaxf(m, __shfl_down(m, off));
  __shared__ float red[4];
  const int lane = threadIdx.x & 63, w = threadIdx.x >> 6;
  if (lane == 0) red[w] = m;
  __syncthreads();
  if (threadIdx.x == 0) {
    const float mm = fmaxf(fmaxf(red[0], red[1]), fmaxf(red[2], red[3]));
    atomicMax(reinterpret_cast<unsigned int*>(out), __float_as_uint(mm));
  }
}

__global__ __launch_bounds__(256) void quant_kernel(
    const float* __restrict__ x, unsigned short* __restrict__ q,
    const float* __restrict__ amax_p, long n) {
  const float s = QMAX / fmaxf(amax_p[0], 1e-8f);
  const long stride = (long)gridDim.x * blockDim.x * 4;
  for (long i = ((long)blockIdx.x * blockDim.x + threadIdx.x) * 4; i < n; i += stride) {
    const float4 v = *reinterpret_cast<const float4*>(x + i);
    ushort4 o;
    o.x = quant_bf16(v.x, s);
    o.y = quant_bf16(v.y, s);
    o.z = quant_bf16(v.z, s);
    o.w = quant_bf16(v.w, s);
    *reinterpret_cast<ushort4*>(q + i) = o;
  }
}

__global__ __launch_bounds__(256) void quant8_kernel(
    const float* __restrict__ x, signed char* __restrict__ q,
    const float* __restrict__ amax_p, long n) {
  const float s = QMAX / fmaxf(amax_p[0], 1e-8f);
  const long stride = (long)gridDim.x * blockDim.x * 8;
  for (long i = ((long)blockIdx.x * blockDim.x + threadIdx.x) * 8; i < n; i += stride) {
    const float4 v0 = *reinterpret_cast<const float4*>(x + i);
    const float4 v1 = *reinterpret_cast<const float4*>(x + i + 4);
    uint2 o; o.x = pack4_i8(v0, s); o.y = pack4_i8(v1, s);
    *reinterpret_cast<uint2*>(q + i) = o;
  }
}

// ===========================================================================
// gemm_s8: int8 GEMM, NO residual. gbf[m][n] = bf16((i32 dot)*inv_s + b[n])
// 128x128 tile, BK=128 (8 iters), 256 thr (4 waves 2x2), mfma_i32_16x16x64_i8
// (2 K-slices/iter -> 32 MFMA/iter).  K-loop = r7-validated 2-barrier counted
// double buffer:
//   [iter it] stage tile it+1 -> buf[(it+1)&1] ; vmcnt(8) ; s_barrier ;
//             ds_read buf[it&1] + 32 MFMA ; s_barrier
// Ledger: (RAW) vmcnt(8) retires own-wave tile-it loads (8 newer outstanding);
// barrier collectivizes. (WAR) buf[(it+1)&1] was read in iter it-1; all waves
// passed iter-(it-1)'s bottom barrier before iter-it's stage issues.
// Row = 128 B = 8 x 16B chunks -> G4 swizzle for D=128: chunk ^= row&7,
// applied BOTH sides (inverse-swizzled global source + swizzled ds_read).
// ks=1 fragment offset = ks=0 offset ^ 64.  LDS 64 KB -> 2 blocks/CU.
// Epilogue: bf16 LDS-bounce -> 16B-coalesced stores (r5/r6-validated).
// ===========================================================================
#define BMs 128
#define BNs 128
#define BKs8 128
#define NIT8 (H_DIM / BKs8) /* 8 */

__global__ __launch_bounds__(256) void gemm_s8_kernel(
    const signed char* __restrict__ Aq8, const signed char* __restrict__ Wq8,
    const float* __restrict__ bias, const float* __restrict__ scales,
    unsigned short* __restrict__ gbf, int M) {
  // K-loop: As 2x16384 @0, Bs 2x16384 @32768 = 64 KB.
  // Epilogue bounce reuses [0..34815] as 128 rows x 136 ushorts.
  __shared__ __attribute__((aligned(16))) char SM8[65536];
  char* As = SM8;            // [2][128*128] i8
  char* Bs = SM8 + 32768;    // [2][128*128] i8

  const int nwg = (M / BMs) * 8;
  const int orig = blockIdx.x;
  const int cpx = nwg >> 3;
  const int wg = ((nwg & 7) == 0) ? ((orig & 7) * cpx + (orig >> 3)) : orig;
  const int bn = wg & 7, bm = wg >> 3;      // bn fast -> A panel L2 reuse
  const int m0 = bm * BMs, n0 = bn * BNs;

  const int t = threadIdx.x;
  const int lane = t & 63, wid = t >> 6;
  const int wr = wid >> 1, wc = wid & 1;
  const int lrow = lane & 15, lgrp = lane >> 4;

  const float amax_h = fmaxf(scales[0], 1e-8f);
  const float amax_w = fmaxf(scales[1], 1e-8f);
  const float inv_s = (amax_h * amax_w) / (QMAX * QMAX);

  // staging: 1024 16B chunks per 128x128 tile; chunk c -> row c>>3, slot c&7;
  // global source chunk inverse-swizzled: slot ^ (row&7).  4 chunks/thread
  // per operand (c = t + 256*j).
  unsigned gsrc[4];
  int ldst[4];
#pragma unroll
  for (int j = 0; j < 4; ++j) {
    const int c = t + 256 * j;
    const int row = c >> 3, slot = c & 7;
    gsrc[j] = (unsigned)row * H_DIM + (unsigned)(((slot ^ (row & 7))) * 16);
    ldst[j] = c * 16;
  }
  const signed char* Ag = Aq8 + (size_t)m0 * H_DIM;
  const signed char* Bg = Wq8 + (size_t)n0 * H_DIM;

#define STAGE_T8(BUF, KQ)                                                      \
  { _Pragma("unroll")                                                          \
    for (int j = 0; j < 4; ++j)                                                \
      __builtin_amdgcn_global_load_lds((gmem_void*)(Ag + gsrc[j] + (KQ)),      \
          (lds_void*)(As + (BUF)*16384 + ldst[j]), 16, 0, 0);                  \
    _Pragma("unroll")                                                          \
    for (int j = 0; j < 4; ++j)                                                \
      __builtin_amdgcn_global_load_lds((gmem_void*)(Bg + gsrc[j] + (KQ)),      \
          (lds_void*)(Bs + (BUF)*16384 + ldst[j]), 16, 0, 0); }

  // per-thread swizzled LDS read offsets (bytes), ks=0; ks=1 = offset ^ 64.
  int offA[4], offB[4];
#pragma unroll
  for (int i = 0; i < 4; ++i) {
    const int r = wr * 64 + i * 16 + lrow;
    offA[i] = r * 128 + ((lgrp ^ (r & 7)) * 16);
  }
#pragma unroll
  for (int j = 0; j < 4; ++j) {
    const int r = wc * 64 + j * 16 + lrow;
    offB[j] = r * 128 + ((lgrp ^ (r & 7)) * 16);
  }

  i32x4 acc[4][4];
#pragma unroll
  for (int i = 0; i < 4; i++)
#pragma unroll
    for (int j = 0; j < 4; j++)
#pragma unroll
      for (int r = 0; r < 4; r++) acc[i][j][r] = 0;

  // prologue: tile 0 -> buf 0 (8 loads/thread in flight)
  STAGE_T8(0, 0)

  for (int it = 0; it < NIT8; ++it) {
    const int cur = it & 1, nxt = cur ^ 1;
    if (it + 1 < NIT8) {
      STAGE_T8(nxt, (unsigned)((it + 1) * BKs8))
      asm volatile("s_waitcnt vmcnt(8)" ::: "memory");  // tile it landed; it+1 in flight
    } else {
      asm volatile("s_waitcnt vmcnt(0)" ::: "memory");  // drain final tile
    }
    __builtin_amdgcn_s_barrier();                        // collective: tile it ready
    __builtin_amdgcn_sched_barrier(0);

#pragma unroll
    for (int ks = 0; ks < 2; ++ks) {
      i32x4 af[4], bfr[4];
      const int kx = ks * 64;
#pragma unroll
      for (int i = 0; i < 4; ++i)
        af[i] = *reinterpret_cast<const i32x4*>(As + cur * 16384 + (offA[i] ^ kx));
#pragma unroll
      for (int j = 0; j < 4; ++j)
        bfr[j] = *reinterpret_cast<const i32x4*>(Bs + cur * 16384 + (offB[j] ^ kx));
      __builtin_amdgcn_s_setprio(1);
#pragma unroll
      for (int i = 0; i < 4; ++i)
#pragma unroll
        for (int j = 0; j < 4; ++j)
          acc[i][j] = __builtin_amdgcn_mfma_i32_16x16x64_i8(af[i], bfr[j], acc[i][j], 0, 0, 0);
      __builtin_amdgcn_s_setprio(0);
    }
    __builtin_amdgcn_s_barrier();                        // all waves done reading cur
  }
#undef STAGE_T8
  __syncthreads();  // drain before bounce overwrites LDS

  // epilogue: g = bf16((float)acc*inv_s + bias) -> LDS bounce -> coalesced
  unsigned short* SMu = reinterpret_cast<unsigned short*>(SM8);
#pragma unroll
  for (int j = 0; j < 4; ++j) {
    const int cl = wc * 64 + j * 16 + lrow;
    const float bv = bias[n0 + cl];
#pragma unroll
    for (int i = 0; i < 4; ++i) {
      const int rl0 = wr * 64 + i * 16 + lgrp * 4;
#pragma unroll
      for (int r = 0; r < 4; ++r)
        SMu[(rl0 + r) * 136 + cl] = f2bf_rne((float)acc[i][j][r] * inv_s + bv);
    }
  }
  __syncthreads();
  {
    const int e_row = t >> 1, e_half = t & 1;
    unsigned short* dst = gbf + (size_t)(m0 + e_row) * H_DIM + n0 + e_half * 64;
    const unsigned short* src = SMu + e_row * 136 + e_half * 64;
#pragma unroll
    for (int c = 0; c < 8; ++c)
      *reinterpret_cast<u16x8*>(dst + c * 8) =
          *reinterpret_cast<const u16x8*>(src + c * 8);
  }
}

// ---------------------------------------------------------------------------
// ln_resid (r6-validated): y = bf16 g + fp32 resid; LayerNorm -> fp32 out.
// ---------------------------------------------------------------------------
__global__ __launch_bounds__(256) void ln_resid_kernel(
    const unsigned short* __restrict__ gbf, const float* __restrict__ resid,
    const float* __restrict__ gamma, const float* __restrict__ beta,
    float* __restrict__ out) {
  const int rl = threadIdx.x >> 7;
  const int c0 = (threadIdx.x & 127) * 8;
  const size_t base = ((size_t)blockIdx.x * 2 + rl) * H_DIM + c0;

  const u16x8 g = *reinterpret_cast<const u16x8*>(gbf + base);
  const float4 rA = *reinterpret_cast<const float4*>(resid + base);
  const float4 rB = *reinterpret_cast<const float4*>(resid + base + 4);
  float v[8];
  v[0] = bf2f(g[0]) + rA.x; v[1] = bf2f(g[1]) + rA.y;
  v[2] = bf2f(g[2]) + rA.z; v[3] = bf2f(g[3]) + rA.w;
  v[4] = bf2f(g[4]) + rB.x; v[5] = bf2f(g[5]) + rB.y;
  v[6] = bf2f(g[6]) + rB.z; v[7] = bf2f(g[7]) + rB.w;

  float s = 0.f, ss = 0.f;
#pragma unroll
  for (int k = 0; k < 8; ++k) { s += v[k]; ss += v[k] * v[k]; }
#pragma unroll
  for (int off = 32; off > 0; off >>= 1) {
    s += __shfl_down(s, off);
    ss += __shfl_down(ss, off);
  }
  __shared__ float red[4][2];
  const int lane = threadIdx.x & 63, w = threadIdx.x >> 6;
  if (lane == 0) { red[w][0] = s; red[w][1] = ss; }
  __syncthreads();
  const int wp = rl * 2;
  const float stot = red[wp][0] + red[wp + 1][0];
  const float sstot = red[wp][1] + red[wp + 1][1];
  const float mu = stot * (1.0f / H_DIM);
  const float var = fmaxf(sstot * (1.0f / H_DIM) - mu * mu, 0.f);
  const float rs = rsqrtf(var + 1e-12f);

  const float4 gA = *reinterpret_cast<const float4*>(gamma + c0);
  const float4 gB = *reinterpret_cast<const float4*>(gamma + c0 + 4);
  const float4 bA = *reinterpret_cast<const float4*>(beta + c0);
  const float4 bB = *reinterpret_cast<const float4*>(beta + c0 + 4);
  float4 oA, oB;
  oA.x = (v[0] - mu) * rs * gA.x + bA.x;
  oA.y = (v[1] - mu) * rs * gA.y + bA.y;
  oA.z = (v[2] - mu) * rs * gA.z + bA.z;
  oA.w = (v[3] - mu) * rs * gA.w + bA.w;
  oB.x = (v[4] - mu) * rs * gB.x + bB.x;
  oB.y = (v[5] - mu) * rs * gB.y + bB.y;
  oB.z = (v[6] - mu) * rs * gB.z + bB.z;
  oB.w = (v[7] - mu) * rs * gB.w + bB.w;
  *reinterpret_cast<float4*>(out + base) = oA;
  *reinterpret_cast<float4*>(out + base + 4) = oB;
}

// ===========================================================================
// Tier-3 fallback (round-1 validated): fused-quant bf16 GEMM + LN.
// ===========================================================================
#define BM 128
#define BN 128
#define BK 32

__global__ __launch_bounds__(256, 2) void gemm_fused_kernel(
    const float* __restrict__ A, const unsigned short* __restrict__ Wq,
    const float* __restrict__ bias, const float* __restrict__ resid,
    const float* __restrict__ scales, float* __restrict__ out, int M) {
  __shared__ unsigned short Asf[BM][40];
  __shared__ unsigned short Bsf[BN][40];
  const int nbm = M / BM;
  const int bm = blockIdx.x % nbm, bn = blockIdx.x / nbm;
  const int m0 = bm * BM, n0 = bn * BN;
  const int t = threadIdx.x;
  const int lane = t & 63, wid = t >> 6;
  const int wr = wid >> 1, wc = wid & 1;
  const int lrow = lane & 15, lgrp = lane >> 4;
  const float amax_h = fmaxf(scales[0], 1e-8f);
  const float amax_w = fmaxf(scales[1], 1e-8f);
  const float sh = QMAX / amax_h;
  const float inv_s = (amax_h * amax_w) / (QMAX * QMAX);
  f32x4 acc[4][4];
#pragma unroll
  for (int i = 0; i < 4; i++)
#pragma unroll
    for (int j = 0; j < 4; j++)
#pragma unroll
      for (int r = 0; r < 4; r++) acc[i][j][r] = 0.f;
  for (int k0 = 0; k0 < H_DIM; k0 += BK) {
#pragma unroll
    for (int j = 0; j < 4; ++j) {
      const int f = j * 256 + t;
      const int r = f >> 3, c4 = f & 7;
      const float4 v = *reinterpret_cast<const float4*>(A + (size_t)(m0 + r) * H_DIM + k0 + c4 * 4);
      ushort4 q;
      q.x = quant_bf16(v.x, sh); q.y = quant_bf16(v.y, sh);
      q.z = quant_bf16(v.z, sh); q.w = quant_bf16(v.w, sh);
      *reinterpret_cast<ushort4*>(&Asf[r][c4 * 4]) = q;
    }
#pragma unroll
    for (int j = 0; j < 2; ++j) {
      const int f = j * 256 + t;
      const int r = f >> 2, cb = f & 3;
      const uint4 v = *reinterpret_cast<const uint4*>(Wq + (size_t)(n0 + r) * H_DIM + k0 + cb * 8);
      *reinterpret_cast<uint4*>(&Bsf[r][cb * 8]) = v;
    }
    __syncthreads();
    bf16x8 af[4], bfr[4];
#pragma unroll
    for (int i = 0; i < 4; i++)
      af[i] = *reinterpret_cast<const bf16x8*>(&Asf[wr * 64 + i * 16 + lrow][lgrp * 8]);
#pragma unroll
    for (int j = 0; j < 4; j++)
      bfr[j] = *reinterpret_cast<const bf16x8*>(&Bsf[wc * 64 + j * 16 + lrow][lgrp * 8]);
#pragma unroll
    for (int i = 0; i < 4; i++)
#pragma unroll
      for (int j = 0; j < 4; j++)
        acc[i][j] = __builtin_amdgcn_mfma_f32_16x16x32_bf16(af[i], bfr[j], acc[i][j], 0, 0, 0);
    __syncthreads();
  }
#pragma unroll
  for (int j = 0; j < 4; j++) {
    const int col = n0 + wc * 64 + j * 16 + lrow;
    const float bv = bias[col];
#pragma unroll
    for (int i = 0; i < 4; i++) {
      const int row0 = m0 + wr * 64 + i * 16 + lgrp * 4;
#pragma unroll
      for (int r = 0; r < 4; r++) {
        const size_t off = (size_t)(row0 + r) * H_DIM + col;
        out[off] = acc[i][j][r] * inv_s + bv + resid[off];
      }
    }
  }
}

__global__ __launch_bounds__(256) void ln_kernel(
    float* __restrict__ y, const float* __restrict__ gamma,
    const float* __restrict__ beta) {
  const size_t base = (size_t)blockIdx.x * H_DIM + threadIdx.x * 4;
  const float4 v = *reinterpret_cast<const float4*>(y + base);
  float s = v.x + v.y + v.z + v.w;
  float ss = v.x * v.x + v.y * v.y + v.z * v.z + v.w * v.w;
#pragma unroll
  for (int off = 32; off > 0; off >>= 1) {
    s += __shfl_down(s, off);
    ss += __shfl_down(ss, off);
  }
  __shared__ float red[8];
  const int lane = threadIdx.x & 63, w = threadIdx.x >> 6;
  if (lane == 0) { red[w] = s; red[4 + w] = ss; }
  __syncthreads();
  const float stot = red[0] + red[1] + red[2] + red[3];
  const float sstot = red[4] + red[5] + red[6] + red[7];
  const float mu = stot * (1.0f / H_DIM);
  const float var = fmaxf(sstot * (1.0f / H_DIM) - mu * mu, 0.f);
  const float rs = rsqrtf(var + 1e-12f);
  const float4 g = *reinterpret_cast<const float4*>(gamma + threadIdx.x * 4);
  const float4 b = *reinterpret_cast<const float4*>(beta + threadIdx.x * 4);
  float4 o;
  o.x = (v.x - mu) * rs * g.x + b.x;
  o.y = (v.y - mu) * rs * g.y + b.y;
  o.z = (v.z - mu) * rs * g.z + b.z;
  o.w = (v.w - mu) * rs * g.w + b.w;
  *reinterpret_cast<float4*>(y + base) = o;
}

extern "C" void kernel_launch(void* const* d_in, const int* in_sizes, int n_in,
                              void* d_out, int out_size, void* d_ws, size_t ws_size,
                              hipStream_t stream) {
  const float* hidden = (const float*)d_in[0];
  const float* resid  = (const float*)d_in[1];
  const float* weight = (const float*)d_in[2];
  const float* bias   = (const float*)d_in[3];
  const float* gamma  = (const float*)d_in[4];
  const float* beta   = (const float*)d_in[5];
  float* out = (float*)d_out;

  const long nh = (long)in_sizes[0];   // B*S*H
  const int M = (int)(nh / H_DIM);     // 32768
  const long nw = (long)H_DIM * H_DIM;

  float* scales = (float*)d_ws;
  char* base = (char*)d_ws + 256;
  signed char* Wq8 = (signed char*)base;                    // 1 MB
  signed char* Aq8 = (signed char*)(base + nw);             // nh bytes
  unsigned short* gbf = (unsigned short*)(base + nw + nh);  // nh*2 bytes
  const size_t need1 = 256 + (size_t)nw + (size_t)nh * 3;
  const size_t need3 = 256 + (size_t)nw * 2;

  hipMemsetAsync(d_ws, 0, 8, stream);

  if (ws_size >= need1 && (M % BMs) == 0 && (M % 2) == 0 && (nh % 8) == 0) {
    // ---- main i8 path (r9-validated front-end, BK=128 GEMM) ----
    absmax_clip_kernel<<<2048, 256, 0, stream>>>(hidden, nh, scales + 0);
    absmax_clip_kernel<<<256, 256, 0, stream>>>(weight, nw, scales + 1);
    quant8_kernel<<<512, 256, 0, stream>>>(weight, Wq8, scales + 1, nw);
    quant8_kernel<<<2048, 256, 0, stream>>>(hidden, Aq8, scales + 0, nh);
    gemm_s8_kernel<<<(M / BMs) * (H_DIM / BNs), 256, 0, stream>>>(
        Aq8, Wq8, bias, scales, gbf, M);
    ln_resid_kernel<<<M / 2, 256, 0, stream>>>(gbf, resid, gamma, beta, out);
  } else if (ws_size >= need3 && (M % BM) == 0) {
    // ---- tier-3 bf16 fallback ----
    unsigned short* Wqf = (unsigned short*)base;
    absmax_clip_kernel<<<2048, 256, 0, stream>>>(hidden, nh, scales + 0);
    absmax_clip_kernel<<<256, 256, 0, stream>>>(weight, nw, scales + 1);
    quant_kernel<<<1024, 256, 0, stream>>>(weight, Wqf, scales + 1, nw);
    gemm_fused_kernel<<<(M / BM) * (H_DIM / BN), 256, 0, stream>>>(
        hidden, Wqf, bias, resid, scales, out, M);
    ln_kernel<<<M, 256, 0, stream>>>(out, gamma, beta);
  }
}

// Round 14
// 193.995 us; speedup vs baseline: 1.3443x; 1.0149x over previous
//
#include <hip/hip_runtime.h>
#include <hip/hip_bf16.h>
#include <stdint.h>

#define H_DIM 1024
#define QMAX 127.0f
#define CLIP 2.5f

typedef __attribute__((ext_vector_type(4))) float f32x4;
typedef __attribute__((ext_vector_type(4))) int i32x4;
typedef __attribute__((ext_vector_type(8))) short bf16x8;
typedef __attribute__((ext_vector_type(8))) unsigned short u16x8;
typedef __attribute__((address_space(3))) void lds_void;
typedef const __attribute__((address_space(1))) void gmem_void;

__device__ __forceinline__ unsigned short quant_bf16(float x, float s) {
  const float q = rintf(fminf(fmaxf(x, -CLIP), CLIP) * s);
  return (unsigned short)(__float_as_uint(q) >> 16);
}

__device__ __forceinline__ int quant_i8(float x, float s) {
  return (int)rintf(fminf(fmaxf(x, -CLIP), CLIP) * s);  // in [-127,127]
}

__device__ __forceinline__ unsigned short f2bf_rne(float f) {
  const unsigned u = __float_as_uint(f);
  return (unsigned short)((u + 0x7FFFu + ((u >> 16) & 1u)) >> 16);
}

__device__ __forceinline__ float bf2f(unsigned short u) {
  return __uint_as_float((unsigned)u << 16);
}

__device__ __forceinline__ unsigned pack4_i8(float4 v, float s) {
  return ((unsigned)(unsigned char)(signed char)quant_i8(v.x, s)) |
         ((unsigned)(unsigned char)(signed char)quant_i8(v.y, s) << 8) |
         ((unsigned)(unsigned char)(signed char)quant_i8(v.z, s) << 16) |
         ((unsigned)(unsigned char)(signed char)quant_i8(v.w, s) << 24);
}

// ---------------------------------------------------------------------------
// absmax2: one launch covers BOTH tensors via block-range split.
// blocks [0, NBH): hidden -> scales[0];  [NBH, NBH+NBW): weight -> scales[1].
// ---------------------------------------------------------------------------
#define NBH 2048
#define NBW 256

__global__ __launch_bounds__(256) void absmax2_kernel(
    const float* __restrict__ hidden, long nh,
    const float* __restrict__ weight, long nw, float* __restrict__ scales) {
  const bool is_w = (blockIdx.x >= NBH);
  const float* x = is_w ? weight : hidden;
  const long n = is_w ? nw : nh;
  const int nb = is_w ? NBW : NBH;
  const int bid = is_w ? (blockIdx.x - NBH) : blockIdx.x;

  float m = 0.f;
  const long stride = (long)nb * blockDim.x * 4;
  for (long i = ((long)bid * blockDim.x + threadIdx.x) * 4; i < n; i += stride) {
    const float4 v = *reinterpret_cast<const float4*>(x + i);
    m = fmaxf(m, fmaxf(fmaxf(fabsf(v.x), fabsf(v.y)), fmaxf(fabsf(v.z), fabsf(v.w))));
  }
  m = fminf(m, CLIP);
#pragma unroll
  for (int off = 32; off > 0; off >>= 1) m = fmaxf(m, __shfl_down(m, off));
  __shared__ float red[4];
  const int lane = threadIdx.x & 63, w = threadIdx.x >> 6;
  if (lane == 0) red[w] = m;
  __syncthreads();
  if (threadIdx.x == 0) {
    const float mm = fmaxf(fmaxf(red[0], red[1]), fmaxf(red[2], red[3]));
    atomicMax(reinterpret_cast<unsigned int*>(scales + (is_w ? 1 : 0)),
              __float_as_uint(mm));
  }
}

// ---------------------------------------------------------------------------
// quant8_both: one launch quantizes BOTH tensors to i8 (block-range split).
// ---------------------------------------------------------------------------
#define QBH 2048
#define QBW 128

__global__ __launch_bounds__(256) void quant8_both_kernel(
    const float* __restrict__ hidden, signed char* __restrict__ Aq8, long nh,
    const float* __restrict__ weight, signed char* __restrict__ Wq8, long nw,
    const float* __restrict__ scales) {
  const bool is_w = (blockIdx.x >= QBH);
  const float* x = is_w ? weight : hidden;
  signed char* q = is_w ? Wq8 : Aq8;
  const long n = is_w ? nw : nh;
  const int nb = is_w ? QBW : QBH;
  const int bid = is_w ? (blockIdx.x - QBH) : blockIdx.x;
  const float s = QMAX / fmaxf(scales[is_w ? 1 : 0], 1e-8f);

  const long stride = (long)nb * blockDim.x * 8;
  for (long i = ((long)bid * blockDim.x + threadIdx.x) * 8; i < n; i += stride) {
    const float4 v0 = *reinterpret_cast<const float4*>(x + i);
    const float4 v1 = *reinterpret_cast<const float4*>(x + i + 4);
    uint2 o; o.x = pack4_i8(v0, s); o.y = pack4_i8(v1, s);
    *reinterpret_cast<uint2*>(q + i) = o;
  }
}

// ---------------------------------------------------------------------------
// Legacy single-tensor kernels (tier-3 fallback path).
// ---------------------------------------------------------------------------
__global__ __launch_bounds__(256) void absmax_clip_kernel(
    const float* __restrict__ x, long n, float* __restrict__ out) {
  float m = 0.f;
  const long stride = (long)gridDim.x * blockDim.x * 4;
  for (long i = ((long)blockIdx.x * blockDim.x + threadIdx.x) * 4; i < n; i += stride) {
    const float4 v = *reinterpret_cast<const float4*>(x + i);
    m = fmaxf(m, fmaxf(fmaxf(fabsf(v.x), fabsf(v.y)), fmaxf(fabsf(v.z), fabsf(v.w))));
  }
  m = fminf(m, CLIP);
#pragma unroll
  for (int off = 32; off > 0; off >>= 1) m = fmaxf(m, __shfl_down(m, off));
  __shared__ float red[4];
  const int lane = threadIdx.x & 63, w = threadIdx.x >> 6;
  if (lane == 0) red[w] = m;
  __syncthreads();
  if (threadIdx.x == 0) {
    const float mm = fmaxf(fmaxf(red[0], red[1]), fmaxf(red[2], red[3]));
    atomicMax(reinterpret_cast<unsigned int*>(out), __float_as_uint(mm));
  }
}

__global__ __launch_bounds__(256) void quant_kernel(
    const float* __restrict__ x, unsigned short* __restrict__ q,
    const float* __restrict__ amax_p, long n) {
  const float s = QMAX / fmaxf(amax_p[0], 1e-8f);
  const long stride = (long)gridDim.x * blockDim.x * 4;
  for (long i = ((long)blockIdx.x * blockDim.x + threadIdx.x) * 4; i < n; i += stride) {
    const float4 v = *reinterpret_cast<const float4*>(x + i);
    ushort4 o;
    o.x = quant_bf16(v.x, s);
    o.y = quant_bf16(v.y, s);
    o.z = quant_bf16(v.z, s);
    o.w = quant_bf16(v.w, s);
    *reinterpret_cast<ushort4*>(q + i) = o;
  }
}

// ===========================================================================
// gemm_s8 (r13-validated): int8 GEMM, NO residual.
// gbf[m][n] = bf16((i32 dot)*inv_s + b[n]).  128x128 tile, BK=128 (8 iters),
// mfma_i32_16x16x64_i8 (32 MFMA/iter), 2-barrier counted-vmcnt double buffer,
// D=128 XOR swizzle both-sides (0 conflicts), bf16 LDS-bounce epilogue.
// ===========================================================================
#define BMs 128
#define BNs 128
#define BKs8 128
#define NIT8 (H_DIM / BKs8) /* 8 */

__global__ __launch_bounds__(256) void gemm_s8_kernel(
    const signed char* __restrict__ Aq8, const signed char* __restrict__ Wq8,
    const float* __restrict__ bias, const float* __restrict__ scales,
    unsigned short* __restrict__ gbf, int M) {
  __shared__ __attribute__((aligned(16))) char SM8[65536];
  char* As = SM8;            // [2][128*128] i8
  char* Bs = SM8 + 32768;    // [2][128*128] i8

  const int nwg = (M / BMs) * 8;
  const int orig = blockIdx.x;
  const int cpx = nwg >> 3;
  const int wg = ((nwg & 7) == 0) ? ((orig & 7) * cpx + (orig >> 3)) : orig;
  const int bn = wg & 7, bm = wg >> 3;      // bn fast -> A panel L2 reuse
  const int m0 = bm * BMs, n0 = bn * BNs;

  const int t = threadIdx.x;
  const int lane = t & 63, wid = t >> 6;
  const int wr = wid >> 1, wc = wid & 1;
  const int lrow = lane & 15, lgrp = lane >> 4;

  const float amax_h = fmaxf(scales[0], 1e-8f);
  const float amax_w = fmaxf(scales[1], 1e-8f);
  const float inv_s = (amax_h * amax_w) / (QMAX * QMAX);

  unsigned gsrc[4];
  int ldst[4];
#pragma unroll
  for (int j = 0; j < 4; ++j) {
    const int c = t + 256 * j;
    const int row = c >> 3, slot = c & 7;
    gsrc[j] = (unsigned)row * H_DIM + (unsigned)(((slot ^ (row & 7))) * 16);
    ldst[j] = c * 16;
  }
  const signed char* Ag = Aq8 + (size_t)m0 * H_DIM;
  const signed char* Bg = Wq8 + (size_t)n0 * H_DIM;

#define STAGE_T8(BUF, KQ)                                                      \
  { _Pragma("unroll")                                                          \
    for (int j = 0; j < 4; ++j)                                                \
      __builtin_amdgcn_global_load_lds((gmem_void*)(Ag + gsrc[j] + (KQ)),      \
          (lds_void*)(As + (BUF)*16384 + ldst[j]), 16, 0, 0);                  \
    _Pragma("unroll")                                                          \
    for (int j = 0; j < 4; ++j)                                                \
      __builtin_amdgcn_global_load_lds((gmem_void*)(Bg + gsrc[j] + (KQ)),      \
          (lds_void*)(Bs + (BUF)*16384 + ldst[j]), 16, 0, 0); }

  int offA[4], offB[4];
#pragma unroll
  for (int i = 0; i < 4; ++i) {
    const int r = wr * 64 + i * 16 + lrow;
    offA[i] = r * 128 + ((lgrp ^ (r & 7)) * 16);
  }
#pragma unroll
  for (int j = 0; j < 4; ++j) {
    const int r = wc * 64 + j * 16 + lrow;
    offB[j] = r * 128 + ((lgrp ^ (r & 7)) * 16);
  }

  i32x4 acc[4][4];
#pragma unroll
  for (int i = 0; i < 4; i++)
#pragma unroll
    for (int j = 0; j < 4; j++)
#pragma unroll
      for (int r = 0; r < 4; r++) acc[i][j][r] = 0;

  STAGE_T8(0, 0)

  for (int it = 0; it < NIT8; ++it) {
    const int cur = it & 1, nxt = cur ^ 1;
    if (it + 1 < NIT8) {
      STAGE_T8(nxt, (unsigned)((it + 1) * BKs8))
      asm volatile("s_waitcnt vmcnt(8)" ::: "memory");
    } else {
      asm volatile("s_waitcnt vmcnt(0)" ::: "memory");
    }
    __builtin_amdgcn_s_barrier();
    __builtin_amdgcn_sched_barrier(0);

#pragma unroll
    for (int ks = 0; ks < 2; ++ks) {
      i32x4 af[4], bfr[4];
      const int kx = ks * 64;
#pragma unroll
      for (int i = 0; i < 4; ++i)
        af[i] = *reinterpret_cast<const i32x4*>(As + cur * 16384 + (offA[i] ^ kx));
#pragma unroll
      for (int j = 0; j < 4; ++j)
        bfr[j] = *reinterpret_cast<const i32x4*>(Bs + cur * 16384 + (offB[j] ^ kx));
      __builtin_amdgcn_s_setprio(1);
#pragma unroll
      for (int i = 0; i < 4; ++i)
#pragma unroll
        for (int j = 0; j < 4; ++j)
          acc[i][j] = __builtin_amdgcn_mfma_i32_16x16x64_i8(af[i], bfr[j], acc[i][j], 0, 0, 0);
      __builtin_amdgcn_s_setprio(0);
    }
    __builtin_amdgcn_s_barrier();
  }
#undef STAGE_T8
  __syncthreads();

  unsigned short* SMu = reinterpret_cast<unsigned short*>(SM8);
#pragma unroll
  for (int j = 0; j < 4; ++j) {
    const int cl = wc * 64 + j * 16 + lrow;
    const float bv = bias[n0 + cl];
#pragma unroll
    for (int i = 0; i < 4; ++i) {
      const int rl0 = wr * 64 + i * 16 + lgrp * 4;
#pragma unroll
      for (int r = 0; r < 4; ++r)
        SMu[(rl0 + r) * 136 + cl] = f2bf_rne((float)acc[i][j][r] * inv_s + bv);
    }
  }
  __syncthreads();
  {
    const int e_row = t >> 1, e_half = t & 1;
    unsigned short* dst = gbf + (size_t)(m0 + e_row) * H_DIM + n0 + e_half * 64;
    const unsigned short* src = SMu + e_row * 136 + e_half * 64;
#pragma unroll
    for (int c = 0; c < 8; ++c)
      *reinterpret_cast<u16x8*>(dst + c * 8) =
          *reinterpret_cast<const u16x8*>(src + c * 8);
  }
}

// ---------------------------------------------------------------------------
// ln_resid (r6-validated): y = bf16 g + fp32 resid; LayerNorm -> fp32 out.
// ---------------------------------------------------------------------------
__global__ __launch_bounds__(256) void ln_resid_kernel(
    const unsigned short* __restrict__ gbf, const float* __restrict__ resid,
    const float* __restrict__ gamma, const float* __restrict__ beta,
    float* __restrict__ out) {
  const int rl = threadIdx.x >> 7;
  const int c0 = (threadIdx.x & 127) * 8;
  const size_t base = ((size_t)blockIdx.x * 2 + rl) * H_DIM + c0;

  const u16x8 g = *reinterpret_cast<const u16x8*>(gbf + base);
  const float4 rA = *reinterpret_cast<const float4*>(resid + base);
  const float4 rB = *reinterpret_cast<const float4*>(resid + base + 4);
  float v[8];
  v[0] = bf2f(g[0]) + rA.x; v[1] = bf2f(g[1]) + rA.y;
  v[2] = bf2f(g[2]) + rA.z; v[3] = bf2f(g[3]) + rA.w;
  v[4] = bf2f(g[4]) + rB.x; v[5] = bf2f(g[5]) + rB.y;
  v[6] = bf2f(g[6]) + rB.z; v[7] = bf2f(g[7]) + rB.w;

  float s = 0.f, ss = 0.f;
#pragma unroll
  for (int k = 0; k < 8; ++k) { s += v[k]; ss += v[k] * v[k]; }
#pragma unroll
  for (int off = 32; off > 0; off >>= 1) {
    s += __shfl_down(s, off);
    ss += __shfl_down(ss, off);
  }
  __shared__ float red[4][2];
  const int lane = threadIdx.x & 63, w = threadIdx.x >> 6;
  if (lane == 0) { red[w][0] = s; red[w][1] = ss; }
  __syncthreads();
  const int wp = rl * 2;
  const float stot = red[wp][0] + red[wp + 1][0];
  const float sstot = red[wp][1] + red[wp + 1][1];
  const float mu = stot * (1.0f / H_DIM);
  const float var = fmaxf(sstot * (1.0f / H_DIM) - mu * mu, 0.f);
  const float rs = rsqrtf(var + 1e-12f);

  const float4 gA = *reinterpret_cast<const float4*>(gamma + c0);
  const float4 gB = *reinterpret_cast<const float4*>(gamma + c0 + 4);
  const float4 bA = *reinterpret_cast<const float4*>(beta + c0);
  const float4 bB = *reinterpret_cast<const float4*>(beta + c0 + 4);
  float4 oA, oB;
  oA.x = (v[0] - mu) * rs * gA.x + bA.x;
  oA.y = (v[1] - mu) * rs * gA.y + bA.y;
  oA.z = (v[2] - mu) * rs * gA.z + bA.z;
  oA.w = (v[3] - mu) * rs * gA.w + bA.w;
  oB.x = (v[4] - mu) * rs * gB.x + bB.x;
  oB.y = (v[5] - mu) * rs * gB.y + bB.y;
  oB.z = (v[6] - mu) * rs * gB.z + bB.z;
  oB.w = (v[7] - mu) * rs * gB.w + bB.w;
  *reinterpret_cast<float4*>(out + base) = oA;
  *reinterpret_cast<float4*>(out + base + 4) = oB;
}

// ===========================================================================
// Tier-3 fallback (round-1 validated): fused-quant bf16 GEMM + LN.
// ===========================================================================
#define BM 128
#define BN 128
#define BK 32

__global__ __launch_bounds__(256, 2) void gemm_fused_kernel(
    const float* __restrict__ A, const unsigned short* __restrict__ Wq,
    const float* __restrict__ bias, const float* __restrict__ resid,
    const float* __restrict__ scales, float* __restrict__ out, int M) {
  __shared__ unsigned short Asf[BM][40];
  __shared__ unsigned short Bsf[BN][40];
  const int nbm = M / BM;
  const int bm = blockIdx.x % nbm, bn = blockIdx.x / nbm;
  const int m0 = bm * BM, n0 = bn * BN;
  const int t = threadIdx.x;
  const int lane = t & 63, wid = t >> 6;
  const int wr = wid >> 1, wc = wid & 1;
  const int lrow = lane & 15, lgrp = lane >> 4;
  const float amax_h = fmaxf(scales[0], 1e-8f);
  const float amax_w = fmaxf(scales[1], 1e-8f);
  const float sh = QMAX / amax_h;
  const float inv_s = (amax_h * amax_w) / (QMAX * QMAX);
  f32x4 acc[4][4];
#pragma unroll
  for (int i = 0; i < 4; i++)
#pragma unroll
    for (int j = 0; j < 4; j++)
#pragma unroll
      for (int r = 0; r < 4; r++) acc[i][j][r] = 0.f;
  for (int k0 = 0; k0 < H_DIM; k0 += BK) {
#pragma unroll
    for (int j = 0; j < 4; ++j) {
      const int f = j * 256 + t;
      const int r = f >> 3, c4 = f & 7;
      const float4 v = *reinterpret_cast<const float4*>(A + (size_t)(m0 + r) * H_DIM + k0 + c4 * 4);
      ushort4 q;
      q.x = quant_bf16(v.x, sh); q.y = quant_bf16(v.y, sh);
      q.z = quant_bf16(v.z, sh); q.w = quant_bf16(v.w, sh);
      *reinterpret_cast<ushort4*>(&Asf[r][c4 * 4]) = q;
    }
#pragma unroll
    for (int j = 0; j < 2; ++j) {
      const int f = j * 256 + t;
      const int r = f >> 2, cb = f & 3;
      const uint4 v = *reinterpret_cast<const uint4*>(Wq + (size_t)(n0 + r) * H_DIM + k0 + cb * 8);
      *reinterpret_cast<uint4*>(&Bsf[r][cb * 8]) = v;
    }
    __syncthreads();
    bf16x8 af[4], bfr[4];
#pragma unroll
    for (int i = 0; i < 4; i++)
      af[i] = *reinterpret_cast<const bf16x8*>(&Asf[wr * 64 + i * 16 + lrow][lgrp * 8]);
#pragma unroll
    for (int j = 0; j < 4; j++)
      bfr[j] = *reinterpret_cast<const bf16x8*>(&Bsf[wc * 64 + j * 16 + lrow][lgrp * 8]);
#pragma unroll
    for (int i = 0; i < 4; i++)
#pragma unroll
      for (int j = 0; j < 4; j++)
        acc[i][j] = __builtin_amdgcn_mfma_f32_16x16x32_bf16(af[i], bfr[j], acc[i][j], 0, 0, 0);
    __syncthreads();
  }
#pragma unroll
  for (int j = 0; j < 4; j++) {
    const int col = n0 + wc * 64 + j * 16 + lrow;
    const float bv = bias[col];
#pragma unroll
    for (int i = 0; i < 4; i++) {
      const int row0 = m0 + wr * 64 + i * 16 + lgrp * 4;
#pragma unroll
      for (int r = 0; r < 4; r++) {
        const size_t off = (size_t)(row0 + r) * H_DIM + col;
        out[off] = acc[i][j][r] * inv_s + bv + resid[off];
      }
    }
  }
}

__global__ __launch_bounds__(256) void ln_kernel(
    float* __restrict__ y, const float* __restrict__ gamma,
    const float* __restrict__ beta) {
  const size_t base = (size_t)blockIdx.x * H_DIM + threadIdx.x * 4;
  const float4 v = *reinterpret_cast<const float4*>(y + base);
  float s = v.x + v.y + v.z + v.w;
  float ss = v.x * v.x + v.y * v.y + v.z * v.z + v.w * v.w;
#pragma unroll
  for (int off = 32; off > 0; off >>= 1) {
    s += __shfl_down(s, off);
    ss += __shfl_down(ss, off);
  }
  __shared__ float red[8];
  const int lane = threadIdx.x & 63, w = threadIdx.x >> 6;
  if (lane == 0) { red[w] = s; red[4 + w] = ss; }
  __syncthreads();
  const float stot = red[0] + red[1] + red[2] + red[3];
  const float sstot = red[4] + red[5] + red[6] + red[7];
  const float mu = stot * (1.0f / H_DIM);
  const float var = fmaxf(sstot * (1.0f / H_DIM) - mu * mu, 0.f);
  const float rs = rsqrtf(var + 1e-12f);
  const float4 g = *reinterpret_cast<const float4*>(gamma + threadIdx.x * 4);
  const float4 b = *reinterpret_cast<const float4*>(beta + threadIdx.x * 4);
  float4 o;
  o.x = (v.x - mu) * rs * g.x + b.x;
  o.y = (v.y - mu) * rs * g.y + b.y;
  o.z = (v.z - mu) * rs * g.z + b.z;
  o.w = (v.w - mu) * rs * g.w + b.w;
  *reinterpret_cast<float4*>(y + base) = o;
}

extern "C" void kernel_launch(void* const* d_in, const int* in_sizes, int n_in,
                              void* d_out, int out_size, void* d_ws, size_t ws_size,
                              hipStream_t stream) {
  const float* hidden = (const float*)d_in[0];
  const float* resid  = (const float*)d_in[1];
  const float* weight = (const float*)d_in[2];
  const float* bias   = (const float*)d_in[3];
  const float* gamma  = (const float*)d_in[4];
  const float* beta   = (const float*)d_in[5];
  float* out = (float*)d_out;

  const long nh = (long)in_sizes[0];   // B*S*H
  const int M = (int)(nh / H_DIM);     // 32768
  const long nw = (long)H_DIM * H_DIM;

  float* scales = (float*)d_ws;
  char* base = (char*)d_ws + 256;
  signed char* Wq8 = (signed char*)base;                    // 1 MB
  signed char* Aq8 = (signed char*)(base + nw);             // nh bytes
  unsigned short* gbf = (unsigned short*)(base + nw + nh);  // nh*2 bytes
  const size_t need1 = 256 + (size_t)nw + (size_t)nh * 3;
  const size_t need3 = 256 + (size_t)nw * 2;

  hipMemsetAsync(d_ws, 0, 8, stream);

  if (ws_size >= need1 && (M % BMs) == 0 && (M % 2) == 0 && (nh % 8) == 0 && (nw % 8) == 0) {
    // ---- main i8 path: 4 dispatches total ----
    absmax2_kernel<<<NBH + NBW, 256, 0, stream>>>(hidden, nh, weight, nw, scales);
    quant8_both_kernel<<<QBH + QBW, 256, 0, stream>>>(hidden, Aq8, nh, weight, Wq8, nw, scales);
    gemm_s8_kernel<<<(M / BMs) * (H_DIM / BNs), 256, 0, stream>>>(
        Aq8, Wq8, bias, scales, gbf, M);
    ln_resid_kernel<<<M / 2, 256, 0, stream>>>(gbf, resid, gamma, beta, out);
  } else if (ws_size >= need3 && (M % BM) == 0) {
    // ---- tier-3 bf16 fallback ----
    unsigned short* Wqf = (unsigned short*)base;
    absmax_clip_kernel<<<2048, 256, 0, stream>>>(hidden, nh, scales + 0);
    absmax_clip_kernel<<<256, 256, 0, stream>>>(weight, nw, scales + 1);
    quant_kernel<<<1024, 256, 0, stream>>>(weight, Wqf, scales + 1, nw);
    gemm_fused_kernel<<<(M / BM) * (H_DIM / BN), 256, 0, stream>>>(
        hidden, Wqf, bias, resid, scales, out, M);
    ln_kernel<<<M, 256, 0, stream>>>(out, gamma, beta);
  }
}